// Round 4
// baseline (12506.021 us; speedup 1.0000x reference)
//
#include <hip/hip_runtime.h>
#include <math.h>

#define NL 24
#define NB 64
#define TPB 256

// ---------------- ws layout (float units) ----------------
#define RING_F   3133440              // ring: [64 batches][765 rows][64 ch]
#define PK_CONV  RING_F               // conv pack : 24*4*4*256 f4 = 393216 fl
#define PK_RES   (PK_CONV + 393216)   // res  pack : 24*4*4*64  f4 = 98304 fl
#define PK_SKIP  (PK_RES  + 98304)    // skip pack : 24*4*8*128 f4 = 393216 fl
#define PK_O0    (PK_SKIP + 393216)   // out0 pack : 4*16*256   f4 = 65536 fl
#define PK_O1    (PK_O0   + 65536)    // out1 pack : 65536 fl
#define PK_SBT   (PK_O1   + 65536)    // 256 fl: sum of skip biases over layers
#define EP_F     (PK_SBT  + 256)      // epoch-tagged mailboxes (u64), 8B aligned
#define EX_OFF   0                    // [64][4][64]  xnew partials
#define ESK_OFF  16384                // [64][4][256] skip partials
#define EH_OFF   81920                // [64][4][64]  h0 gather
#define EA_OFF   98304                // [64][4][2]   argmax (val, idx)
#define EP_U64   98816

#define AL(p)   __hip_atomic_load((p),       __ATOMIC_RELAXED, __HIP_MEMORY_SCOPE_AGENT)
#define AS(p,v) __hip_atomic_store((p), (v), __ATOMIC_RELAXED, __HIP_MEMORY_SCOPE_AGENT)

__device__ __forceinline__ float dot4(float4 a, float4 b) {
    return fmaf(a.x, b.x, fmaf(a.y, b.y, fmaf(a.z, b.z, a.w * b.w)));
}

// barrier WITHOUT vmcnt drain: weight prefetches stay in flight
__device__ __forceinline__ void bar() {
    asm volatile("s_waitcnt lgkmcnt(0)" ::: "memory");
    __builtin_amdgcn_s_barrier();
    asm volatile("" ::: "memory");
}

__device__ __forceinline__ unsigned long long spin1(const unsigned long long* p, unsigned ep) {
    unsigned long long v = AL(p);
    while ((unsigned)(v >> 32) != ep) { __builtin_amdgcn_s_sleep(1); v = AL(p); }
    return v;
}

// ---------------- repack: gather weights into per-thread coalesced slices ----------------
__global__ void repack(const float* __restrict__ conv_k, const float* __restrict__ res_w,
                       const float* __restrict__ skip_w, const float* __restrict__ out0_w,
                       const float* __restrict__ out1_w, const float* __restrict__ skip_b,
                       float* __restrict__ ws)
{
    const int f = blockIdx.x * blockDim.x + threadIdx.x;
    float4 v = make_float4(0.f, 0.f, 0.f, 0.f);
    float* e = (float*)&v;
    float4* dst;
    if (f < 98304) {                       // conv
        const int tid = f & 255;
        int r = f >> 8;
        const int jj = r & 3; r >>= 2;
        const int s  = r & 3; const int i = r >> 2;
        const int wv = tid >> 6, lv = tid & 63;
        const int j   = s*16 + wv*4 + (lv >> 4);
        const int col = (jj < 2) ? j : j + 64;
        const int k0  = (lv & 15)*8 + (jj & 1)*4;
#pragma unroll
        for (int m = 0; m < 4; ++m) {
            const int k = k0 + m;
            const int tap = k >> 6, cin = k & 63;
            e[m] = conv_k[((size_t)(i*2 + tap)*64 + cin)*128 + col];
        }
        dst = (float4*)(ws + PK_CONV) + f;
    } else if (f < 122880) {               // res
        const int fr = f - 98304;
        const int lv = fr & 63, jj = (fr >> 6) & 3, s = (fr >> 8) & 3, i = fr >> 10;
        const int k0 = s*16 + jj*4;
#pragma unroll
        for (int m = 0; m < 4; ++m)
            e[m] = res_w[((size_t)i*64 + k0 + m)*64 + lv];
        dst = (float4*)(ws + PK_RES) + fr;
    } else if (f < 221184) {               // skip
        const int fs = f - 122880;
        const int u = fs & 127, jj = (fs >> 7) & 7, s = (fs >> 10) & 3, i = fs >> 12;
        const int col = 2*u + (jj >> 2);
        const int k0  = s*16 + (jj & 3)*4;
#pragma unroll
        for (int m = 0; m < 4; ++m)
            e[m] = skip_w[((size_t)i*64 + k0 + m)*256 + col];
        dst = (float4*)(ws + PK_SKIP) + fs;
    } else if (f < 237568) {               // out0
        const int fo = f - 221184;
        const int tid = fo & 255, jj = (fo >> 8) & 15, s = fo >> 12;
        const int col = s*64 + (tid & 63);
        const int k0  = (tid >> 6)*64 + jj*4;
#pragma unroll
        for (int m = 0; m < 4; ++m)
            e[m] = out0_w[(size_t)(k0 + m)*256 + col];
        dst = (float4*)(ws + PK_O0) + fo;
    } else if (f < 253952) {               // out1
        const int fo = f - 237568;
        const int tid = fo & 255, jj = (fo >> 8) & 15, s = fo >> 12;
        const int col = s*64 + (tid & 63);
        const int k0  = (tid >> 6)*64 + jj*4;
#pragma unroll
        for (int m = 0; m < 4; ++m)
            e[m] = out1_w[(size_t)(k0 + m)*256 + col];
        dst = (float4*)(ws + PK_O1) + fo;
    } else if (f < 254016) {               // sbt = sum_i skip_b[i]
        const int fb = f - 253952;
#pragma unroll
        for (int m = 0; m < 4; ++m) {
            float sum = 0.f;
            for (int i = 0; i < NL; ++i) sum += skip_b[i*256 + fb*4 + m];
            e[m] = sum;
        }
        dst = (float4*)(ws + PK_SBT) + fb;
    } else return;
    *dst = v;
}

// per-thread register weight fragments (double-buffered)
struct Frag { float4 c[4]; float4 r[4]; float4 k[8]; };

// ---------------- generator: 4 slice-blocks per batch, epoch-mailbox sync ----------------
__global__ __launch_bounds__(TPB)
void wavenet_gen(const int* __restrict__ seed, const float* __restrict__ embed,
                 const float* __restrict__ conv_b, const float* __restrict__ res_b,
                 const float* __restrict__ out0_b, const float* __restrict__ out1_b,
                 const int* __restrict__ Tptr, float* __restrict__ out,
                 float* __restrict__ ws)
{
    const int b   = blockIdx.x & (NB - 1);
    const int sl  = blockIdx.x >> 6;
    const int tid = threadIdx.x;
    const int w   = tid >> 6;
    const int l   = tid & 63;
    const int T   = *Tptr;

    __shared__ __align__(16) float x2[128];       // [0:64) x_last, [64:128) x_cur
    __shared__ __align__(16) float g16[16];       // this slice's gate values
    __shared__ __align__(16) float sktot[256];
    __shared__ __align__(16) float h0f[256];
    __shared__ __align__(16) float redu[256];
    __shared__ __align__(16) float cbA[NL*16], cbB[NL*16];
    __shared__ __align__(16) float rbS[NL*64];
    __shared__ __align__(16) float o0bS[256], o1bS[256], sbtS[256];

    float* ring = ws + (size_t)b * (765 * 64);
    const float4* packf4 = (const float4*)ws;
    unsigned long long* EPB = (unsigned long long*)(ws + EP_F);
    unsigned long long* EX  = EPB + EX_OFF  + (size_t)b * 4 * 64;
    unsigned long long* ESK = EPB + ESK_OFF + (size_t)b * 4 * 256;
    unsigned long long* EH  = EPB + EH_OFF  + (size_t)b * 4 * 64;
    unsigned long long* EA  = EPB + EA_OFF  + (size_t)b * 4 * 2;

    // ---- stage biases in LDS ----
    for (int idx = tid; idx < NL * 16; idx += TPB) {
        const int i = idx >> 4, p = idx & 15;
        cbA[idx] = conv_b[i*128 + sl*16 + p];
        cbB[idx] = conv_b[i*128 + 64 + sl*16 + p];
    }
    for (int idx = tid; idx < NL * 64; idx += TPB) rbS[idx] = res_b[idx];
    o0bS[tid] = out0_b[tid];
    o1bS[tid] = out1_b[tid];
    sbtS[tid] = ws[PK_SBT + tid];

    float e0r = 0.f, xl8r = 0.f, xl16r = 0.f;   // d=1 shortcut registers (wave0 / wave3)
    float skv0 = 0.f, skv1 = 0.f;               // skip accumulators (waves 1,2)
    const int smp0 = seed[b];
    if (w == 0) {
        e0r = embed[(size_t)smp0 * 64 + l];
        x2[64 + l] = e0r;
        x2[l] = 0.f;
    }
    __syncthreads();

    Frag FA, FB;
    {   // prefetch layer 0 into FA
        const float4* pc = packf4 + (PK_CONV >> 2) + (size_t)((0*4 + sl)*4)*256 + tid;
#pragma unroll
        for (int jj = 0; jj < 4; ++jj) FA.c[jj] = pc[jj*256];
        if (w == 3) {
            const float4* pr = packf4 + (PK_RES >> 2) + (size_t)((0*4 + sl)*4)*64 + l;
#pragma unroll
            for (int jj = 0; jj < 4; ++jj) FA.r[jj] = pr[jj*64];
        } else if (w == 1 || w == 2) {
            const float4* ps = packf4 + (PK_SKIP >> 2) + (size_t)((0*4 + sl)*8)*128 + (tid - 64);
#pragma unroll
            for (int jj = 0; jj < 8; ++jj) FA.k[jj] = ps[jj*128];
        }
    }

    float* out_pred = out + (size_t)b * T;
    float* out_logb = out + (size_t)NB * T;

#pragma unroll 1
    for (int t = 0; t < T; ++t) {

        auto layer = [&](Frag& cur, Frag& nxt, const int i) {
            const int inx = (i + 1 < NL) ? (i + 1) : 0;
            {   // prefetch next layer's fragments
                const float4* pc = packf4 + (PK_CONV >> 2) + (size_t)((inx*4 + sl)*4)*256 + tid;
#pragma unroll
                for (int jj = 0; jj < 4; ++jj) nxt.c[jj] = pc[jj*256];
                if (w == 3) {
                    const float4* pr = packf4 + (PK_RES >> 2) + (size_t)((inx*4 + sl)*4)*64 + l;
#pragma unroll
                    for (int jj = 0; jj < 4; ++jj) nxt.r[jj] = pr[jj*64];
                } else if (w == 1 || w == 2) {
                    const float4* ps = packf4 + (PK_SKIP >> 2) + (size_t)((inx*4 + sl)*8)*128 + (tid - 64);
#pragma unroll
                    for (int jj = 0; jj < 8; ++jj) nxt.k[jj] = ps[jj*128];
                }
            }
            const int j = i + 1;
            float ringv = 0.f;
            if (w == 3 && j < NL && (j & 7) != 0) {   // early ring read of next layer's x_last
                const int dj  = 1 << (j & 7);
                const int row = 255*(j >> 3) + (dj - 1) + (t & (dj - 1));
                ringv = __uint_as_float(AL((const unsigned int*)&ring[(size_t)row*64 + l]));
            }
            {   // conv + gate (all waves; pair jloc, K-chunk per lane)
                const int jloc = w*4 + (l >> 4);
                const int kc   = (l & 15) * 8;
                const float4 xv0 = *(const float4*)&x2[kc];
                const float4 xv1 = *(const float4*)&x2[kc + 4];
                float hA = dot4(xv0, cur.c[0]) + dot4(xv1, cur.c[1]);
                float hB = dot4(xv0, cur.c[2]) + dot4(xv1, cur.c[3]);
#pragma unroll
                for (int off = 1; off <= 8; off <<= 1) {
                    hA += __shfl_xor(hA, off);
                    hB += __shfl_xor(hB, off);
                }
                if ((l & 15) == 0) {
                    const float aa = hA + cbA[i*16 + jloc];
                    const float bb = hB + cbB[i*16 + jloc];
                    g16[jloc] = tanhf(aa) * (1.f / (1.f + expf(-bb)));
                }
            }
            bar();
            if (w == 3) {
                if (i < NL - 1) {
                    const float4 ga = *(const float4*)&g16[0];
                    const float4 gb = *(const float4*)&g16[4];
                    const float4 gc = *(const float4*)&g16[8];
                    const float4 gd = *(const float4*)&g16[12];
                    const float racc = dot4(ga, cur.r[0]) + dot4(gb, cur.r[1])
                                     + dot4(gc, cur.r[2]) + dot4(gd, cur.r[3]);
                    const unsigned ep = (unsigned)(t*32 + i + 1);
                    asm volatile("s_waitcnt vmcnt(0)" ::: "memory");  // ring read drained pre-publish
                    AS(&EX[(size_t)sl*64 + l],
                       ((unsigned long long)ep << 32) | __float_as_uint(racc));
                    const int s1 = (sl + 1) & 3, s2 = (sl + 2) & 3, s3 = (sl + 3) & 3;
                    const unsigned long long* q1 = &EX[(size_t)s1*64 + l];
                    const unsigned long long* q2 = &EX[(size_t)s2*64 + l];
                    const unsigned long long* q3 = &EX[(size_t)s3*64 + l];
                    unsigned long long v1 = 0, v2 = 0, v3 = 0;
                    bool d1 = false, d2 = false, d3 = false;
                    for (;;) {
                        if (!d1) { v1 = AL(q1); d1 = (unsigned)(v1 >> 32) == ep; }
                        if (!d2) { v2 = AL(q2); d2 = (unsigned)(v2 >> 32) == ep; }
                        if (!d3) { v3 = AL(q3); d3 = (unsigned)(v3 >> 32) == ep; }
                        if (d1 & d2 & d3) break;
                        __builtin_amdgcn_s_sleep(1);
                    }
                    const float f1 = __uint_as_float((unsigned)v1);
                    const float f2 = __uint_as_float((unsigned)v2);
                    const float f3 = __uint_as_float((unsigned)v3);
                    float p0, p1, p2, p3;   // absolute slice order -> bit-identical xnew everywhere
                    if      (sl == 0) { p0 = racc; p1 = f1; p2 = f2; p3 = f3; }
                    else if (sl == 1) { p1 = racc; p2 = f1; p3 = f2; p0 = f3; }
                    else if (sl == 2) { p2 = racc; p3 = f1; p0 = f2; p1 = f3; }
                    else              { p3 = racc; p0 = f1; p1 = f2; p2 = f3; }
                    const float xnew = (x2[64 + l] + rbS[i*64 + l]) + ((p0 + p1) + (p2 + p3));
                    if (sl == 0 && (j & 7) != 0) {   // single writer pushes ring row(j, t)
                        const int dj  = 1 << (j & 7);
                        const int row = 255*(j >> 3) + (dj - 1) + (t & (dj - 1));
                        AS((unsigned int*)&ring[(size_t)row*64 + l], __float_as_uint(xnew));
                    }
                    if      (j == 8)  { x2[l] = xl8r;  xl8r  = xnew; }
                    else if (j == 16) { x2[l] = xl16r; xl16r = xnew; }
                    else              { x2[l] = ringv; }
                    x2[64 + l] = xnew;
                }
            } else if (w == 1 || w == 2) {   // skip partial (runs under wave3's exchange)
                const float4 ga = *(const float4*)&g16[0];
                const float4 gb = *(const float4*)&g16[4];
                const float4 gc = *(const float4*)&g16[8];
                const float4 gd = *(const float4*)&g16[12];
                skv0 += dot4(ga, cur.k[0]) + dot4(gb, cur.k[1]) + dot4(gc, cur.k[2]) + dot4(gd, cur.k[3]);
                skv1 += dot4(ga, cur.k[4]) + dot4(gb, cur.k[5]) + dot4(gc, cur.k[6]) + dot4(gd, cur.k[7]);
            }
            bar();
        };

#pragma unroll 1
        for (int ii = 0; ii < NL; ii += 2) {
            layer(FA, FB, ii);
            layer(FB, FA, ii + 1);
        }

        // ---------------- head ----------------
        const unsigned epS = (unsigned)(t*32 + 28);
        if (w == 1 || w == 2) {
            const int u = tid - 64;
            AS(&ESK[(size_t)sl*256 + 2*u],
               ((unsigned long long)epS << 32) | __float_as_uint(skv0));
            AS(&ESK[(size_t)sl*256 + 2*u + 1],
               ((unsigned long long)epS << 32) | __float_as_uint(skv1));
            skv0 = 0.f; skv1 = 0.f;
        }
        {   // gather full skip vector (absolute slice order sum)
            const unsigned long long* q0 = &ESK[(size_t)0*256 + tid];
            const unsigned long long* q1 = &ESK[(size_t)1*256 + tid];
            const unsigned long long* q2 = &ESK[(size_t)2*256 + tid];
            const unsigned long long* q3 = &ESK[(size_t)3*256 + tid];
            unsigned long long v0 = 0, v1 = 0, v2 = 0, v3 = 0;
            bool d0 = false, d1 = false, d2 = false, d3 = false;
            for (;;) {
                if (!d0) { v0 = AL(q0); d0 = (unsigned)(v0 >> 32) == epS; }
                if (!d1) { v1 = AL(q1); d1 = (unsigned)(v1 >> 32) == epS; }
                if (!d2) { v2 = AL(q2); d2 = (unsigned)(v2 >> 32) == epS; }
                if (!d3) { v3 = AL(q3); d3 = (unsigned)(v3 >> 32) == epS; }
                if (d0 & d1 & d2 & d3) break;
                __builtin_amdgcn_s_sleep(1);
            }
            sktot[tid] = ((__uint_as_float((unsigned)v0) + __uint_as_float((unsigned)v1))
                        + (__uint_as_float((unsigned)v2) + __uint_as_float((unsigned)v3)))
                       + sbtS[tid];
        }
        bar();
        {   // GEMV1: h0 slice
            const float4* pw = packf4 + (PK_O0 >> 2) + (size_t)sl*16*256 + tid;
            float acc = 0.f;
#pragma unroll
            for (int jj = 0; jj < 16; ++jj) {
                const float4 wv = pw[jj*256];
                const float4 xv = *(const float4*)&sktot[w*64 + jj*4];
                acc += dot4(xv, wv);
            }
            redu[tid] = acc;
        }
        bar();
        const unsigned epH = (unsigned)(t*32 + 29);
        if (tid < 64) {
            float h0 = ((redu[tid] + redu[64 + tid]) + (redu[128 + tid] + redu[192 + tid]))
                     + o0bS[sl*64 + tid];
            h0 = fmaxf(h0, 0.f);
            AS(&EH[(size_t)sl*64 + tid], ((unsigned long long)epH << 32) | __float_as_uint(h0));
            h0f[sl*64 + tid] = h0;    // local shortcut for own slice
        }
        if ((tid >> 6) != sl)
            h0f[tid] = __uint_as_float((unsigned)spin1(&EH[(size_t)(tid >> 6)*64 + (tid & 63)], epH));
        bar();
        {   // GEMV2: logits slice
            const float4* pw = packf4 + (PK_O1 >> 2) + (size_t)sl*16*256 + tid;
            float acc = 0.f;
#pragma unroll
            for (int jj = 0; jj < 16; ++jj) {
                const float4 wv = pw[jj*256];
                const float4 xv = *(const float4*)&h0f[w*64 + jj*4];
                acc += dot4(xv, wv);
            }
            redu[tid] = acc;
        }
        bar();
        const unsigned epA = (unsigned)(t*32 + 30);
        if (tid < 64) {
            const float logit = ((redu[tid] + redu[64 + tid]) + (redu[128 + tid] + redu[192 + tid]))
                              + o1bS[sl*64 + tid];
            out_logb[((size_t)b*T + t)*256 + sl*64 + tid] = logit;
            float bv = logit; int bi = sl*64 + tid;
#pragma unroll
            for (int off = 1; off <= 32; off <<= 1) {
                const float ov = __shfl_xor(bv, off);
                const int   oi = __shfl_xor(bi, off);
                if (ov > bv || (ov == bv && oi < bi)) { bv = ov; bi = oi; }
            }
            if (l == 0) {
                AS(&EA[(size_t)sl*2],     ((unsigned long long)epA << 32) | __float_as_uint(bv));
                AS(&EA[(size_t)sl*2 + 1], ((unsigned long long)epA << 32) | (unsigned)bi);
            }
        }
        if (w == 0) {   // final argmax across slices + next-step state
            const int h = l >> 4;
            const unsigned long long* qa = &EA[(size_t)h*2];
            const unsigned long long* qb = &EA[(size_t)h*2 + 1];
            unsigned long long va = 0, vb = 0; bool da = false, db = false;
            for (;;) {
                if (!da) { va = AL(qa); da = (unsigned)(va >> 32) == epA; }
                if (!db) { vb = AL(qb); db = (unsigned)(vb >> 32) == epA; }
                if (da & db) break;
                __builtin_amdgcn_s_sleep(1);
            }
            float av = __uint_as_float((unsigned)va);
            int   ai = (int)(unsigned)vb;
#pragma unroll
            for (int off = 16; off <= 32; off <<= 1) {
                const float ov = __shfl_xor(av, off);
                const int   oi = __shfl_xor(ai, off);
                if (ov > av || (ov == av && oi < ai)) { av = ov; ai = oi; }
            }
            const float eold = e0r;     // x_last(layer0, t+1) = embed[sample_t]
            x2[l] = eold;
            e0r = embed[(size_t)ai*64 + l];
            x2[64 + l] = e0r;
            if (l == 0) {
                const float mw = (float)ai * (2.0f / 255.0f) - 1.0f;
                const float aa = fabsf(mw);
                const float pp = (exp2f(8.0f * aa) - 1.0f) * (1.0f / 255.0f);
                out_pred[t] = (mw < 0.f) ? -pp : pp;
            }
        }
        bar();
    }
}

extern "C" void kernel_launch(void* const* d_in, const int* in_sizes, int n_in,
                              void* d_out, int out_size, void* d_ws, size_t ws_size,
                              hipStream_t stream) {
    const int*   seed   = (const int*)  d_in[0];
    const float* embed  = (const float*)d_in[1];
    const float* conv_k = (const float*)d_in[2];
    const float* conv_b = (const float*)d_in[3];
    const float* res_w  = (const float*)d_in[4];
    const float* res_b  = (const float*)d_in[5];
    const float* skip_w = (const float*)d_in[6];
    const float* skip_b = (const float*)d_in[7];
    const float* out0_w = (const float*)d_in[8];
    const float* out0_b = (const float*)d_in[9];
    const float* out1_w = (const float*)d_in[10];
    const float* out1_b = (const float*)d_in[11];
    const int*   Tptr   = (const int*)  d_in[12];
    float* ws = (float*)d_ws;

    hipMemsetAsync(ws, 0, (size_t)RING_F * 4, stream);                       // zero queue rings
    hipMemsetAsync((char*)d_ws + (size_t)EP_F * 4, 0, (size_t)EP_U64 * 8, stream); // zero mailboxes

    repack<<<dim3(993), dim3(256), 0, stream>>>(conv_k, res_w, skip_w, out0_w, out1_w, skip_b, ws);

    wavenet_gen<<<dim3(256), dim3(TPB), 0, stream>>>(
        seed, embed, conv_b, res_b, out0_b, out1_b, Tptr, (float*)d_out, ws);
}

// Round 7
// 10913.142 us; speedup vs baseline: 1.1460x; 1.1460x over previous
//
#include <hip/hip_runtime.h>
#include <math.h>

#define NL 24
#define NB 64
#define TPB 512
#define QROWS 765
#define QFLOATS ((size_t)NB * QROWS * 64)         // ring: [64][765][64] fp32
#define PACKW_F4 ((size_t)NL * 8 * 18 * 64)       // per-lane packed layer weights (float4 units)

typedef float vf4 __attribute__((ext_vector_type(4)));

// Per-lane register fragment of one layer's weights (18 float4 = 72 floats):
//  v[0..3]  conv col c      = w*8+(l&7), k = (l>>3)*16 + j*4 + m   (k<64: tap0/x_last, k>=64: tap1/x_cur)
//  v[4..7]  conv col c+64, same k
//  v[8..9]  res  col c,      k = (l>>3)*8  + (j-8)*4 + m
//  v[10..13] skip col s0     = w*32+(l&15)*2, k = (l>>4)*16 + (j-10)*4 + m
//  v[14..17] skip col s0+1, same k
struct WB { float4 v[18]; };

__device__ __forceinline__ float hadd4(float4 v) { return (v.x + v.y) + (v.z + v.w); }
__device__ __forceinline__ void fma4(float4& a, float4 x, float4 w) {
    a.x = fmaf(x.x, w.x, a.x); a.y = fmaf(x.y, w.y, a.y);
    a.z = fmaf(x.z, w.z, a.z); a.w = fmaf(x.w, w.w, a.w);
}

// Barrier that does NOT drain vmcnt (register weight prefetches stay in flight).
__device__ __forceinline__ void bar() {
    asm volatile("s_waitcnt lgkmcnt(0)" ::: "memory");
    __builtin_amdgcn_s_barrier();
    asm volatile("" ::: "memory");
}

__device__ __forceinline__ void pf(WB& b, const float4* __restrict__ packW, int i, int w, int l) {
    const float4* p = packW + ((size_t)(i * 8 + w) * 18) * 64 + l;
#pragma unroll
    for (int j = 0; j < 18; ++j) b.v[j] = p[j * 64];
}

// ---------------- repack: swizzle weights into lane-major coalesced layout ----------------
__global__ void repack(const float* __restrict__ conv_k, const float* __restrict__ res_w,
                       const float* __restrict__ skip_w, const float* __restrict__ out0_w,
                       const float* __restrict__ out1_w, float* __restrict__ ws) {
    const int l = threadIdx.x;
    const int bb = blockIdx.x;
    float4* packW = (float4*)(ws + QFLOATS);
    float4* packH = packW + PACKW_F4;
    if (bb < NL * 8) {
        const int i = bb >> 3, w = bb & 7;
        float4* dst = packW + (size_t)bb * 18 * 64 + l;
        const int c  = w * 8 + (l & 7);
        const int kb = (l >> 3) * 16;
#pragma unroll
        for (int j = 0; j < 4; ++j) {           // conv col c
            float4 v;
            int k0 = kb + j * 4;
            v.x = conv_k[(((size_t)i * 2 + ((k0+0) >> 6)) * 64 + ((k0+0) & 63)) * 128 + c];
            v.y = conv_k[(((size_t)i * 2 + ((k0+1) >> 6)) * 64 + ((k0+1) & 63)) * 128 + c];
            v.z = conv_k[(((size_t)i * 2 + ((k0+2) >> 6)) * 64 + ((k0+2) & 63)) * 128 + c];
            v.w = conv_k[(((size_t)i * 2 + ((k0+3) >> 6)) * 64 + ((k0+3) & 63)) * 128 + c];
            dst[j * 64] = v;
        }
#pragma unroll
        for (int j = 0; j < 4; ++j) {           // conv col c+64
            float4 v;
            int k0 = kb + j * 4; int c2 = c + 64;
            v.x = conv_k[(((size_t)i * 2 + ((k0+0) >> 6)) * 64 + ((k0+0) & 63)) * 128 + c2];
            v.y = conv_k[(((size_t)i * 2 + ((k0+1) >> 6)) * 64 + ((k0+1) & 63)) * 128 + c2];
            v.z = conv_k[(((size_t)i * 2 + ((k0+2) >> 6)) * 64 + ((k0+2) & 63)) * 128 + c2];
            v.w = conv_k[(((size_t)i * 2 + ((k0+3) >> 6)) * 64 + ((k0+3) & 63)) * 128 + c2];
            dst[(4 + j) * 64] = v;
        }
        const int kr = (l >> 3) * 8;
#pragma unroll
        for (int j = 0; j < 2; ++j) {           // res col c
            float4 v; int k0 = kr + j * 4;
            v.x = res_w[((size_t)i * 64 + k0 + 0) * 64 + c];
            v.y = res_w[((size_t)i * 64 + k0 + 1) * 64 + c];
            v.z = res_w[((size_t)i * 64 + k0 + 2) * 64 + c];
            v.w = res_w[((size_t)i * 64 + k0 + 3) * 64 + c];
            dst[(8 + j) * 64] = v;
        }
        const int s0 = w * 32 + (l & 15) * 2;
        const int ks = (l >> 4) * 16;
#pragma unroll
        for (int j = 0; j < 4; ++j) {           // skip col s0
            float4 v; int k0 = ks + j * 4;
            v.x = skip_w[((size_t)i * 64 + k0 + 0) * 256 + s0];
            v.y = skip_w[((size_t)i * 64 + k0 + 1) * 256 + s0];
            v.z = skip_w[((size_t)i * 64 + k0 + 2) * 256 + s0];
            v.w = skip_w[((size_t)i * 64 + k0 + 3) * 256 + s0];
            dst[(10 + j) * 64] = v;
        }
#pragma unroll
        for (int j = 0; j < 4; ++j) {           // skip col s0+1
            float4 v; int k0 = ks + j * 4; int s1 = s0 + 1;
            v.x = skip_w[((size_t)i * 64 + k0 + 0) * 256 + s1];
            v.y = skip_w[((size_t)i * 64 + k0 + 1) * 256 + s1];
            v.z = skip_w[((size_t)i * 64 + k0 + 2) * 256 + s1];
            v.w = skip_w[((size_t)i * 64 + k0 + 3) * 256 + s1];
            dst[(14 + j) * 64] = v;
        }
    } else {
        const int hb = bb - NL * 8;             // 0..15: [which 0/1][wave]
        const int which = hb >> 3, w = hb & 7;
        const float* W = which ? out1_w : out0_w;
        float4* dst = packH + (size_t)hb * 32 * 64 + l;
        const int c  = w * 32 + (l & 31);
        const int kb = (l >> 5) * 128;
        for (int j = 0; j < 32; ++j) {
            float4 v; int k0 = kb + j * 4;
            v.x = W[(size_t)(k0 + 0) * 256 + c];
            v.y = W[(size_t)(k0 + 1) * 256 + c];
            v.z = W[(size_t)(k0 + 2) * 256 + c];
            v.w = W[(size_t)(k0 + 3) * 256 + c];
            dst[j * 64] = v;
        }
    }
}

// ---------------- main generator: one block per batch, 8 waves ----------------
__global__ __launch_bounds__(TPB, 2)
void wavenet_gen(const int* __restrict__ seed,
                 const float* __restrict__ embed,
                 const float* __restrict__ conv_b,
                 const float* __restrict__ res_b,
                 const float* __restrict__ skip_b,
                 const float* __restrict__ out0_b,
                 const float* __restrict__ out1_b,
                 const int* __restrict__ Tptr,
                 float* __restrict__ out,
                 float* __restrict__ ws)
{
    const int b   = blockIdx.x;
    const int tid = threadIdx.x;
    const int w   = tid >> 6;
    const int l   = tid & 63;
    const int T   = *Tptr;

    __shared__ __align__(16) float x2[128];          // [0:64) x_last, [64:128) x_cur
    __shared__ __align__(16) float gg[64];
    __shared__ __align__(16) float sk_lds[256];
    __shared__ __align__(16) float h0_lds[256];
    __shared__ __align__(16) float ebt[256 * 64];    // embed table
    __shared__ __align__(16) float cb[NL * 128];
    __shared__ __align__(16) float rb[NL * 64];
    __shared__ __align__(16) float sb[NL * 256];
    __shared__ __align__(16) float o0b[256], o1b[256];
    __shared__ float wmaxv[8];
    __shared__ int   wmaxi[8];

    float* q = ws + (size_t)b * (QROWS * 64);
    const float4* packW = (const float4*)(ws + QFLOATS);
    const float4* packH = packW + PACKW_F4;

    // ---- init: zero queue rings (NT stores: don't pollute L2); stage LDS ----
    {
        vf4* q4 = (vf4*)q;
        const vf4 z = (vf4){0.f, 0.f, 0.f, 0.f};
        for (int idx = tid; idx < QROWS * 64 / 4; idx += TPB)
            __builtin_nontemporal_store(z, &q4[idx]);
        const float4* s4; float4* d4;
        s4 = (const float4*)embed;  d4 = (float4*)ebt;
        for (int idx = tid; idx < 256 * 64 / 4; idx += TPB) d4[idx] = s4[idx];
        s4 = (const float4*)conv_b; d4 = (float4*)cb;
        for (int idx = tid; idx < NL * 128 / 4; idx += TPB) d4[idx] = s4[idx];
        s4 = (const float4*)res_b;  d4 = (float4*)rb;
        for (int idx = tid; idx < NL * 64 / 4; idx += TPB) d4[idx] = s4[idx];
        s4 = (const float4*)skip_b; d4 = (float4*)sb;
        for (int idx = tid; idx < NL * 256 / 4; idx += TPB) d4[idx] = s4[idx];
        s4 = (const float4*)out0_b; d4 = (float4*)o0b;
        for (int idx = tid; idx < 64; idx += TPB) d4[idx] = s4[idx];
        s4 = (const float4*)out1_b; d4 = (float4*)o1b;
        for (int idx = tid; idx < 64; idx += TPB) d4[idx] = s4[idx];
    }
    __syncthreads();
    if (tid < 64) {
        x2[tid] = 0.f;                                   // x_last(layer0, t=0) = 0
        const int smp = seed[b];
        x2[64 + tid] = ebt[smp * 64 + tid];              // x_cur = embed[seed]
    }
    __syncthreads();

    // triple-buffered weight fragments: compute layer i from slot i%3,
    // prefetch layer i+2 into slot (i+2)%3 at the top of layer i.
    WB A, B, C;
    pf(A, packW, 0, w, l);
    pf(B, packW, 1, w, l);

    float* out_pred = out + (size_t)b * T;
    float* out_log  = out + (size_t)NB * T + (size_t)b * T * 256;

    const int c   = w * 8 + (l & 7);       // conv/res column
    const int kb  = (l >> 3) * 16;         // conv K-chunk
    const int kr  = (l >> 3) * 8;          // res K-chunk
    const int ks  = (l >> 4) * 16;         // skip K-chunk
    const int s0  = w * 32 + (l & 15) * 2; // skip cols s0, s0+1
    const int c2  = w * 32 + (l & 31);     // head column
    const int kb2 = (l >> 5) * 128;        // head K-half

    for (int t = 0; t < T; ++t) {
        float skv0 = 0.f, skv1 = 0.f;

        auto layer = [&](WB& cur, WB& pre, const int i) {
            const int inx  = (i + 1 < NL) ? (i + 1) : 0;      // next layer (ring read)
            const int inx2 = (i + 2 < NL) ? (i + 2) : i + 2 - NL; // prefetch target
            // ---------------- phase alpha ----------------
            float xlnext = 0.f;
            if (w == 7) {                                  // early ring read: next layer's x_last
                const int d2 = 1 << (inx & 7);
                const int row2 = 255 * (inx >> 3) + (d2 - 1) + (t & (d2 - 1));
                xlnext = q[(size_t)row2 * 64 + l];
            }
            pf(pre, packW, inx2, w, l);                    // depth-2 prefetch
            if (w == 6) {                                  // queue push (NT: write-once stream)
                const int d = 1 << (i & 7);
                const int row = 255 * (i >> 3) + (d - 1) + (t & (d - 1));
                __builtin_nontemporal_store(x2[64 + l], &q[(size_t)row * 64 + l]);
            }
            // conv partials (own 16-K chunk, cols c and c+64)
            float4 xk0 = *(const float4*)&x2[kb];
            float4 xk1 = *(const float4*)&x2[kb + 4];
            float4 xk2 = *(const float4*)&x2[kb + 8];
            float4 xk3 = *(const float4*)&x2[kb + 12];
            float4 aA = make_float4(0.f, 0.f, 0.f, 0.f);
            float4 aB = make_float4(0.f, 0.f, 0.f, 0.f);
            fma4(aA, xk0, cur.v[0]); fma4(aA, xk1, cur.v[1]);
            fma4(aA, xk2, cur.v[2]); fma4(aA, xk3, cur.v[3]);
            fma4(aB, xk0, cur.v[4]); fma4(aB, xk1, cur.v[5]);
            fma4(aB, xk2, cur.v[6]); fma4(aB, xk3, cur.v[7]);
            float hA = hadd4(aA), hB = hadd4(aB);
            hA += __shfl_xor(hA, 8);  hB += __shfl_xor(hB, 8);
            hA += __shfl_xor(hA, 16); hB += __shfl_xor(hB, 16);
            hA += __shfl_xor(hA, 32); hB += __shfl_xor(hB, 32);
            hA += cb[i * 128 + c];
            hB += cb[i * 128 + 64 + c];
            const float g = tanhf(hA) * (1.f / (1.f + expf(-hB)));
            if (l < 8) gg[w * 8 + l] = g;
            bar();
            // ---------------- phase beta ----------------
            // res partial
            float4 gr0 = *(const float4*)&gg[kr];
            float4 gr1 = *(const float4*)&gg[kr + 4];
            float4 ra = make_float4(0.f, 0.f, 0.f, 0.f);
            fma4(ra, gr0, cur.v[8]); fma4(ra, gr1, cur.v[9]);
            float racc = hadd4(ra);
            racc += __shfl_xor(racc, 8);
            racc += __shfl_xor(racc, 16);
            racc += __shfl_xor(racc, 32);
            const float xnew = x2[64 + c] + racc + rb[i * 64 + c];
            // skip partial
            float4 gs0 = *(const float4*)&gg[ks];
            float4 gs1 = *(const float4*)&gg[ks + 4];
            float4 gs2 = *(const float4*)&gg[ks + 8];
            float4 gs3 = *(const float4*)&gg[ks + 12];
            float4 sa0 = make_float4(0.f, 0.f, 0.f, 0.f);
            float4 sa1 = make_float4(0.f, 0.f, 0.f, 0.f);
            fma4(sa0, gs0, cur.v[10]); fma4(sa0, gs1, cur.v[11]);
            fma4(sa0, gs2, cur.v[12]); fma4(sa0, gs3, cur.v[13]);
            fma4(sa1, gs0, cur.v[14]); fma4(sa1, gs1, cur.v[15]);
            fma4(sa1, gs2, cur.v[16]); fma4(sa1, gs3, cur.v[17]);
            float ss0 = hadd4(sa0), ss1 = hadd4(sa1);
            ss0 += __shfl_xor(ss0, 16); ss1 += __shfl_xor(ss1, 16);
            ss0 += __shfl_xor(ss0, 32); ss1 += __shfl_xor(ss1, 32);
            skv0 += ss0 + sb[i * 256 + s0];
            skv1 += ss1 + sb[i * 256 + s0 + 1];
            if (l < 8) x2[64 + w * 8 + l] = xnew;   // residual out -> x_cur
            if (w == 7) x2[l] = xlnext;             // next layer's x_last
            bar();
        };

#pragma unroll 1
        for (int ii = 0; ii < NL; ii += 3) {
            layer(A, C, ii);
            layer(B, A, ii + 1);
            layer(C, B, ii + 2);
        }

        // ---------------- head ----------------
        if (l < 16) { sk_lds[s0] = skv0; sk_lds[s0 + 1] = skv1; }
        bar();
        // GEMV1: h0 = relu(skip @ out0_w + b0)
        {
            const float4* hp = packH + ((size_t)w * 32) * 64 + l;
            float4 ha = make_float4(0.f, 0.f, 0.f, 0.f);
#pragma unroll 8
            for (int cc = 0; cc < 32; ++cc) {
                float4 wv = hp[cc * 64];
                float4 sv = *(const float4*)&sk_lds[kb2 + cc * 4];
                fma4(ha, sv, wv);
            }
            float hs = hadd4(ha);
            hs += __shfl_xor(hs, 32);
            const float h0 = fmaxf(hs + o0b[c2], 0.f);
            if (l < 32) h0_lds[c2] = h0;
        }
        bar();
        // GEMV2: logits = h0 @ out1_w + b1
        float logit;
        {
            const float4* hp = packH + ((size_t)(8 + w) * 32) * 64 + l;
            float4 la = make_float4(0.f, 0.f, 0.f, 0.f);
#pragma unroll 8
            for (int cc = 0; cc < 32; ++cc) {
                float4 wv = hp[cc * 64];
                float4 hv = *(const float4*)&h0_lds[kb2 + cc * 4];
                fma4(la, hv, wv);
            }
            float ls = hadd4(la);
            ls += __shfl_xor(ls, 32);
            logit = ls + o1b[c2];
            if (l < 32)
                __builtin_nontemporal_store(logit, &out_log[(size_t)t * 256 + c2]);
        }
        // wave-local argmax over its 32 columns (first-index tie-break)
        {
            float bv = logit; int bi = c2;
#pragma unroll
            for (int off = 1; off <= 16; off <<= 1) {
                const float ov = __shfl_xor(bv, off);
                const int   oi = __shfl_xor(bi, off);
                if (ov > bv || (ov == bv && oi < bi)) { bv = ov; bi = oi; }
            }
            if (l == 0) { wmaxv[w] = bv; wmaxi[w] = bi; }
        }
        bar();
        // final: cross-wave argmax, next-step state, mu-law output
        {
            float fv = wmaxv[0]; int fi = wmaxi[0];
#pragma unroll
            for (int ww = 1; ww < 8; ++ww) {
                const float vv = wmaxv[ww]; const int vi = wmaxi[ww];
                if (vv > fv || (vv == fv && vi < fi)) { fv = vv; fi = vi; }
            }
            if (tid < 64) x2[64 + tid] = ebt[fi * 64 + tid];
            if (tid == 0) {
                const float mw = (float)fi * (2.0f / 255.0f) - 1.0f;
                const float a  = fabsf(mw);
                const float p  = (exp2f(8.0f * a) - 1.0f) * (1.0f / 255.0f);
                __builtin_nontemporal_store((mw < 0.f) ? -p : p, &out_pred[t]);
            }
        }
        bar();
    }
}

extern "C" void kernel_launch(void* const* d_in, const int* in_sizes, int n_in,
                              void* d_out, int out_size, void* d_ws, size_t ws_size,
                              hipStream_t stream) {
    const int*   seed   = (const int*)  d_in[0];
    const float* embed  = (const float*)d_in[1];
    const float* conv_k = (const float*)d_in[2];
    const float* conv_b = (const float*)d_in[3];
    const float* res_w  = (const float*)d_in[4];
    const float* res_b  = (const float*)d_in[5];
    const float* skip_w = (const float*)d_in[6];
    const float* skip_b = (const float*)d_in[7];
    const float* out0_w = (const float*)d_in[8];
    const float* out0_b = (const float*)d_in[9];
    const float* out1_w = (const float*)d_in[10];
    const float* out1_b = (const float*)d_in[11];
    const int*   Tptr   = (const int*)  d_in[12];

    repack<<<dim3(NL * 8 + 16), dim3(64), 0, stream>>>(
        conv_k, res_w, skip_w, out0_w, out1_w, (float*)d_ws);

    wavenet_gen<<<dim3(NB), dim3(TPB), 0, stream>>>(
        seed, embed, conv_b, res_b, skip_b, out0_b, out1_b, Tptr,
        (float*)d_out, (float*)d_ws);
}

// Round 8
// 6691.086 us; speedup vs baseline: 1.8691x; 1.6310x over previous
//
#include <hip/hip_runtime.h>
#include <math.h>

#define NL 24
#define NB 64
#define TPB 512
#define QROWS 765
#define QFLOATS ((size_t)NB * QROWS * 64)         // ring: [64][765][64] fp32
#define PACKW_F4 ((size_t)NL * 8 * 18 * 64)       // per-lane packed layer weights (float4 units)

typedef float vf4 __attribute__((ext_vector_type(4)));

// Per-lane register fragment of one layer's weights (18 float4 = 72 floats):
//  v[0..3]  conv col c      = w*8+(l&7), k = (l>>3)*16 + j*4 + m   (k<64: tap0/x_last, k>=64: tap1/x_cur)
//  v[4..7]  conv col c+64, same k
//  v[8..9]  res  col c,      k = (l>>3)*8  + (j-8)*4 + m
//  v[10..13] skip col s0     = w*32+(l&15)*2, k = (l>>4)*16 + (j-10)*4 + m
//  v[14..17] skip col s0+1, same k
struct WB { float4 v[18]; };

__device__ __forceinline__ float hadd4(float4 v) { return (v.x + v.y) + (v.z + v.w); }
__device__ __forceinline__ void fma4(float4& a, float4 x, float4 w) {
    a.x = fmaf(x.x, w.x, a.x); a.y = fmaf(x.y, w.y, a.y);
    a.z = fmaf(x.z, w.z, a.z); a.w = fmaf(x.w, w.w, a.w);
}

// Barrier that does NOT drain vmcnt (register weight prefetches stay in flight).
__device__ __forceinline__ void bar() {
    asm volatile("s_waitcnt lgkmcnt(0)" ::: "memory");
    __builtin_amdgcn_s_barrier();
    asm volatile("" ::: "memory");
}

__device__ __forceinline__ void pf(WB& b, const float4* __restrict__ packW, int i, int w, int l) {
    const float4* p = packW + ((size_t)(i * 8 + w) * 18) * 64 + l;
#pragma unroll
    for (int j = 0; j < 18; ++j) b.v[j] = p[j * 64];
}

// ---------------- repack: swizzle weights into lane-major coalesced layout ----------------
__global__ void repack(const float* __restrict__ conv_k, const float* __restrict__ res_w,
                       const float* __restrict__ skip_w, const float* __restrict__ out0_w,
                       const float* __restrict__ out1_w, float* __restrict__ ws) {
    const int l = threadIdx.x;
    const int bb = blockIdx.x;
    float4* packW = (float4*)(ws + QFLOATS);
    float4* packH = packW + PACKW_F4;
    if (bb < NL * 8) {
        const int i = bb >> 3, w = bb & 7;
        float4* dst = packW + (size_t)bb * 18 * 64 + l;
        const int c  = w * 8 + (l & 7);
        const int kb = (l >> 3) * 16;
#pragma unroll
        for (int j = 0; j < 4; ++j) {           // conv col c
            float4 v;
            int k0 = kb + j * 4;
            v.x = conv_k[(((size_t)i * 2 + ((k0+0) >> 6)) * 64 + ((k0+0) & 63)) * 128 + c];
            v.y = conv_k[(((size_t)i * 2 + ((k0+1) >> 6)) * 64 + ((k0+1) & 63)) * 128 + c];
            v.z = conv_k[(((size_t)i * 2 + ((k0+2) >> 6)) * 64 + ((k0+2) & 63)) * 128 + c];
            v.w = conv_k[(((size_t)i * 2 + ((k0+3) >> 6)) * 64 + ((k0+3) & 63)) * 128 + c];
            dst[j * 64] = v;
        }
#pragma unroll
        for (int j = 0; j < 4; ++j) {           // conv col c+64
            float4 v;
            int k0 = kb + j * 4; int c2 = c + 64;
            v.x = conv_k[(((size_t)i * 2 + ((k0+0) >> 6)) * 64 + ((k0+0) & 63)) * 128 + c2];
            v.y = conv_k[(((size_t)i * 2 + ((k0+1) >> 6)) * 64 + ((k0+1) & 63)) * 128 + c2];
            v.z = conv_k[(((size_t)i * 2 + ((k0+2) >> 6)) * 64 + ((k0+2) & 63)) * 128 + c2];
            v.w = conv_k[(((size_t)i * 2 + ((k0+3) >> 6)) * 64 + ((k0+3) & 63)) * 128 + c2];
            dst[(4 + j) * 64] = v;
        }
        const int kr = (l >> 3) * 8;
#pragma unroll
        for (int j = 0; j < 2; ++j) {           // res col c
            float4 v; int k0 = kr + j * 4;
            v.x = res_w[((size_t)i * 64 + k0 + 0) * 64 + c];
            v.y = res_w[((size_t)i * 64 + k0 + 1) * 64 + c];
            v.z = res_w[((size_t)i * 64 + k0 + 2) * 64 + c];
            v.w = res_w[((size_t)i * 64 + k0 + 3) * 64 + c];
            dst[(8 + j) * 64] = v;
        }
        const int s0 = w * 32 + (l & 15) * 2;
        const int ks = (l >> 4) * 16;
#pragma unroll
        for (int j = 0; j < 4; ++j) {           // skip col s0
            float4 v; int k0 = ks + j * 4;
            v.x = skip_w[((size_t)i * 64 + k0 + 0) * 256 + s0];
            v.y = skip_w[((size_t)i * 64 + k0 + 1) * 256 + s0];
            v.z = skip_w[((size_t)i * 64 + k0 + 2) * 256 + s0];
            v.w = skip_w[((size_t)i * 64 + k0 + 3) * 256 + s0];
            dst[(10 + j) * 64] = v;
        }
#pragma unroll
        for (int j = 0; j < 4; ++j) {           // skip col s0+1
            float4 v; int k0 = ks + j * 4; int s1 = s0 + 1;
            v.x = skip_w[((size_t)i * 64 + k0 + 0) * 256 + s1];
            v.y = skip_w[((size_t)i * 64 + k0 + 1) * 256 + s1];
            v.z = skip_w[((size_t)i * 64 + k0 + 2) * 256 + s1];
            v.w = skip_w[((size_t)i * 64 + k0 + 3) * 256 + s1];
            dst[(14 + j) * 64] = v;
        }
    } else {
        const int hb = bb - NL * 8;             // 0..15: [which 0/1][wave]
        const int which = hb >> 3, w = hb & 7;
        const float* W = which ? out1_w : out0_w;
        float4* dst = packH + (size_t)hb * 32 * 64 + l;
        const int c  = w * 32 + (l & 31);
        const int kb = (l >> 5) * 128;
        for (int j = 0; j < 32; ++j) {
            float4 v; int k0 = kb + j * 4;
            v.x = W[(size_t)(k0 + 0) * 256 + c];
            v.y = W[(size_t)(k0 + 1) * 256 + c];
            v.z = W[(size_t)(k0 + 2) * 256 + c];
            v.w = W[(size_t)(k0 + 3) * 256 + c];
            dst[j * 64] = v;
        }
    }
}

// ---------------- main generator: one block per batch, 8 waves, 1 block/CU ----------------
__global__ __launch_bounds__(TPB, 1)
void wavenet_gen(const int* __restrict__ seed,
                 const float* __restrict__ embed,
                 const float* __restrict__ conv_b,
                 const float* __restrict__ res_b,
                 const float* __restrict__ skip_b,
                 const float* __restrict__ out0_b,
                 const float* __restrict__ out1_b,
                 const int* __restrict__ Tptr,
                 float* __restrict__ out,
                 float* __restrict__ ws)
{
    const int b   = blockIdx.x;
    const int tid = threadIdx.x;
    const int w   = tid >> 6;
    const int l   = tid & 63;
    const int T   = *Tptr;

    __shared__ __align__(16) float x2[128];          // [0:64) x_last, [64:128) x_cur
    __shared__ __align__(16) float gg[64];
    __shared__ __align__(16) float sk_lds[256];
    __shared__ __align__(16) float h0_lds[256];
    __shared__ __align__(16) float ebt[256 * 64];    // embed table
    __shared__ __align__(16) float cb[NL * 128];
    __shared__ __align__(16) float rb[NL * 64];
    __shared__ __align__(16) float o0b[256], o1b[256];
    __shared__ __align__(16) float sbt[256];         // sum over layers of skip_b
    __shared__ float wmaxv[8];
    __shared__ int   wmaxi[8];

    float* q = ws + (size_t)b * (QROWS * 64);
    const float4* packW = (const float4*)(ws + QFLOATS);
    const float4* packH = packW + PACKW_F4;

    // ---- init: zero queue rings (NT: write-once until far-future read); stage LDS ----
    {
        vf4* q4 = (vf4*)q;
        const vf4 z = (vf4){0.f, 0.f, 0.f, 0.f};
        for (int idx = tid; idx < QROWS * 64 / 4; idx += TPB)
            __builtin_nontemporal_store(z, &q4[idx]);
        const float4* s4; float4* d4;
        s4 = (const float4*)embed;  d4 = (float4*)ebt;
        for (int idx = tid; idx < 256 * 64 / 4; idx += TPB) d4[idx] = s4[idx];
        s4 = (const float4*)conv_b; d4 = (float4*)cb;
        for (int idx = tid; idx < NL * 128 / 4; idx += TPB) d4[idx] = s4[idx];
        s4 = (const float4*)res_b;  d4 = (float4*)rb;
        for (int idx = tid; idx < NL * 64 / 4; idx += TPB) d4[idx] = s4[idx];
        s4 = (const float4*)out0_b; d4 = (float4*)o0b;
        for (int idx = tid; idx < 64; idx += TPB) d4[idx] = s4[idx];
        s4 = (const float4*)out1_b; d4 = (float4*)o1b;
        for (int idx = tid; idx < 64; idx += TPB) d4[idx] = s4[idx];
        if (tid < 256) {                               // sbt = sum_i skip_b[i]
            float acc = 0.f;
            for (int i = 0; i < NL; ++i) acc += skip_b[i * 256 + tid];
            sbt[tid] = acc;
        }
    }
    __syncthreads();
    if (tid < 64) {
        x2[tid] = 0.f;                                   // x_last(layer0, t=0) = 0
        const int smp = seed[b];
        x2[64 + tid] = ebt[smp * 64 + tid];              // x_cur = embed[seed]
    }
    __syncthreads();

    // double-buffered weight fragments (144 VGPR): prefetch layer i+1 at top of layer i
    WB A, B;
    pf(A, packW, 0, w, l);

    float* out_pred = out + (size_t)b * T;
    float* out_log  = out + (size_t)NB * T + (size_t)b * T * 256;

    const int c   = w * 8 + (l & 7);       // conv/res column
    const int kb  = (l >> 3) * 16;         // conv K-chunk
    const int kr  = (l >> 3) * 8;          // res K-chunk
    const int ks  = (l >> 4) * 16;         // skip K-chunk
    const int s0  = w * 32 + (l & 15) * 2; // skip cols s0, s0+1
    const int c2  = w * 32 + (l & 31);     // head column
    const int kb2 = (l >> 5) * 128;        // head K-half

    for (int t = 0; t < T; ++t) {
        float skv0 = 0.f, skv1 = 0.f;

        auto layer = [&](WB& cur, WB& nxt, const int i) {
            const int inx = (i + 1 < NL) ? (i + 1) : 0;    // next layer (prefetch + ring read)
            // ---------------- phase alpha ----------------
            float xlnext = 0.f;
            if (w == 7) {                                  // early ring read: next layer's x_last
                const int d2 = 1 << (inx & 7);
                const int row2 = 255 * (inx >> 3) + (d2 - 1) + (t & (d2 - 1));
                xlnext = q[(size_t)row2 * 64 + l];
            }
            pf(nxt, packW, inx, w, l);                     // depth-1 register prefetch
            if (w == 6) {                                  // queue push (L2-cached: re-read soon)
                const int d = 1 << (i & 7);
                const int row = 255 * (i >> 3) + (d - 1) + (t & (d - 1));
                q[(size_t)row * 64 + l] = x2[64 + l];
            }
            // conv partials (own 16-K chunk, cols c and c+64)
            float4 xk0 = *(const float4*)&x2[kb];
            float4 xk1 = *(const float4*)&x2[kb + 4];
            float4 xk2 = *(const float4*)&x2[kb + 8];
            float4 xk3 = *(const float4*)&x2[kb + 12];
            float4 aA = make_float4(0.f, 0.f, 0.f, 0.f);
            float4 aB = make_float4(0.f, 0.f, 0.f, 0.f);
            fma4(aA, xk0, cur.v[0]); fma4(aA, xk1, cur.v[1]);
            fma4(aA, xk2, cur.v[2]); fma4(aA, xk3, cur.v[3]);
            fma4(aB, xk0, cur.v[4]); fma4(aB, xk1, cur.v[5]);
            fma4(aB, xk2, cur.v[6]); fma4(aB, xk3, cur.v[7]);
            float hA = hadd4(aA), hB = hadd4(aB);
            hA += __shfl_xor(hA, 8);  hB += __shfl_xor(hB, 8);
            hA += __shfl_xor(hA, 16); hB += __shfl_xor(hB, 16);
            hA += __shfl_xor(hA, 32); hB += __shfl_xor(hB, 32);
            hA += cb[i * 128 + c];
            hB += cb[i * 128 + 64 + c];
            const float g = tanhf(hA) * (1.f / (1.f + expf(-hB)));
            if (l < 8) gg[w * 8 + l] = g;
            bar();
            // ---------------- phase beta ----------------
            // res partial
            float4 gr0 = *(const float4*)&gg[kr];
            float4 gr1 = *(const float4*)&gg[kr + 4];
            float4 ra = make_float4(0.f, 0.f, 0.f, 0.f);
            fma4(ra, gr0, cur.v[8]); fma4(ra, gr1, cur.v[9]);
            float racc = hadd4(ra);
            racc += __shfl_xor(racc, 8);
            racc += __shfl_xor(racc, 16);
            racc += __shfl_xor(racc, 32);
            const float xnew = x2[64 + c] + racc + rb[i * 64 + c];
            // skip partial
            float4 gs0 = *(const float4*)&gg[ks];
            float4 gs1 = *(const float4*)&gg[ks + 4];
            float4 gs2 = *(const float4*)&gg[ks + 8];
            float4 gs3 = *(const float4*)&gg[ks + 12];
            float4 sa0 = make_float4(0.f, 0.f, 0.f, 0.f);
            float4 sa1 = make_float4(0.f, 0.f, 0.f, 0.f);
            fma4(sa0, gs0, cur.v[10]); fma4(sa0, gs1, cur.v[11]);
            fma4(sa0, gs2, cur.v[12]); fma4(sa0, gs3, cur.v[13]);
            fma4(sa1, gs0, cur.v[14]); fma4(sa1, gs1, cur.v[15]);
            fma4(sa1, gs2, cur.v[16]); fma4(sa1, gs3, cur.v[17]);
            float ss0 = hadd4(sa0), ss1 = hadd4(sa1);
            ss0 += __shfl_xor(ss0, 16); ss1 += __shfl_xor(ss1, 16);
            ss0 += __shfl_xor(ss0, 32); ss1 += __shfl_xor(ss1, 32);
            skv0 += ss0;
            skv1 += ss1;
            if (l < 8) x2[64 + w * 8 + l] = xnew;   // residual out -> x_cur
            if (w == 7) x2[l] = xlnext;             // next layer's x_last
            bar();
        };

#pragma unroll 1
        for (int ii = 0; ii < NL; ii += 2) {
            layer(A, B, ii);
            layer(B, A, ii + 1);
        }

        // ---------------- head ----------------
        if (l < 16) { sk_lds[s0] = skv0 + sbt[s0]; sk_lds[s0 + 1] = skv1 + sbt[s0 + 1]; }
        bar();
        // GEMV1: h0 = relu(skip @ out0_w + b0)
        {
            const float4* hp = packH + ((size_t)w * 32) * 64 + l;
            float4 ha = make_float4(0.f, 0.f, 0.f, 0.f);
#pragma unroll 8
            for (int cc = 0; cc < 32; ++cc) {
                float4 wv = hp[cc * 64];
                float4 sv = *(const float4*)&sk_lds[kb2 + cc * 4];
                fma4(ha, sv, wv);
            }
            float hs = hadd4(ha);
            hs += __shfl_xor(hs, 32);
            const float h0 = fmaxf(hs + o0b[c2], 0.f);
            if (l < 32) h0_lds[c2] = h0;
        }
        bar();
        // GEMV2: logits = h0 @ out1_w + b1
        float logit;
        {
            const float4* hp = packH + ((size_t)(8 + w) * 32) * 64 + l;
            float4 la = make_float4(0.f, 0.f, 0.f, 0.f);
#pragma unroll 8
            for (int cc = 0; cc < 32; ++cc) {
                float4 wv = hp[cc * 64];
                float4 hv = *(const float4*)&h0_lds[kb2 + cc * 4];
                fma4(la, hv, wv);
            }
            float ls = hadd4(la);
            ls += __shfl_xor(ls, 32);
            logit = ls + o1b[c2];
            if (l < 32)
                __builtin_nontemporal_store(logit, &out_log[(size_t)t * 256 + c2]);
        }
        // wave-local argmax over its 32 columns (first-index tie-break)
        {
            float bv = logit; int bi = c2;
#pragma unroll
            for (int off = 1; off <= 16; off <<= 1) {
                const float ov = __shfl_xor(bv, off);
                const int   oi = __shfl_xor(bi, off);
                if (ov > bv || (ov == bv && oi < bi)) { bv = ov; bi = oi; }
            }
            if (l == 0) { wmaxv[w] = bv; wmaxi[w] = bi; }
        }
        bar();
        // final: cross-wave argmax, next-step state, mu-law output
        {
            float fv = wmaxv[0]; int fi = wmaxi[0];
#pragma unroll
            for (int ww = 1; ww < 8; ++ww) {
                const float vv = wmaxv[ww]; const int vi = wmaxi[ww];
                if (vv > fv || (vv == fv && vi < fi)) { fv = vv; fi = vi; }
            }
            if (tid < 64) x2[64 + tid] = ebt[fi * 64 + tid];
            if (tid == 0) {
                const float mw = (float)fi * (2.0f / 255.0f) - 1.0f;
                const float a  = fabsf(mw);
                const float p  = (exp2f(8.0f * a) - 1.0f) * (1.0f / 255.0f);
                __builtin_nontemporal_store((mw < 0.f) ? -p : p, &out_pred[t]);
            }
        }
        bar();
    }
}

extern "C" void kernel_launch(void* const* d_in, const int* in_sizes, int n_in,
                              void* d_out, int out_size, void* d_ws, size_t ws_size,
                              hipStream_t stream) {
    const int*   seed   = (const int*)  d_in[0];
    const float* embed  = (const float*)d_in[1];
    const float* conv_k = (const float*)d_in[2];
    const float* conv_b = (const float*)d_in[3];
    const float* res_w  = (const float*)d_in[4];
    const float* res_b  = (const float*)d_in[5];
    const float* skip_w = (const float*)d_in[6];
    const float* skip_b = (const float*)d_in[7];
    const float* out0_w = (const float*)d_in[8];
    const float* out0_b = (const float*)d_in[9];
    const float* out1_w = (const float*)d_in[10];
    const float* out1_b = (const float*)d_in[11];
    const int*   Tptr   = (const int*)  d_in[12];

    repack<<<dim3(NL * 8 + 16), dim3(64), 0, stream>>>(
        conv_k, res_w, skip_w, out0_w, out1_w, (float*)d_ws);

    wavenet_gen<<<dim3(NB), dim3(TPB), 0, stream>>>(
        seed, embed, conv_b, res_b, skip_b, out0_b, out1_b, Tptr,
        (float*)d_out, (float*)d_ws);
}

// Round 9
// 6601.421 us; speedup vs baseline: 1.8944x; 1.0136x over previous
//
#include <hip/hip_runtime.h>
#include <math.h>

#define NL 24
#define NB 64
#define TPB 512
#define QROWS 765
#define QFLOATS ((size_t)NB * QROWS * 64)         // ring: [64][765][64] fp32
#define PACKW_F4 ((size_t)NL * 8 * 18 * 64)       // per-lane packed layer weights (float4 units)

typedef float vf4 __attribute__((ext_vector_type(4)));

// Per-lane register fragment of one layer's weights (18 float4 = 72 floats):
//  v[0..3]  conv col c      = w*8+(l&7), k = (l>>3)*16 + j*4 + m   (k<64: tap0/x_last, k>=64: tap1/x_cur)
//  v[4..7]  conv col c+64, same k
//  v[8..9]  res  col c,      k = (l>>3)*8  + (j-8)*4 + m
//  v[10..13] skip col s0     = w*32+(l&15)*2, k = (l>>4)*16 + (j-10)*4 + m
//  v[14..17] skip col s0+1, same k
struct WB { float4 v[18]; };

__device__ __forceinline__ float hadd4(float4 v) { return (v.x + v.y) + (v.z + v.w); }
__device__ __forceinline__ void fma4(float4& a, float4 x, float4 w) {
    a.x = fmaf(x.x, w.x, a.x); a.y = fmaf(x.y, w.y, a.y);
    a.z = fmaf(x.z, w.z, a.z); a.w = fmaf(x.w, w.w, a.w);
}

// Barrier that does NOT drain vmcnt (register weight prefetches stay in flight).
__device__ __forceinline__ void bar() {
    asm volatile("s_waitcnt lgkmcnt(0)" ::: "memory");
    __builtin_amdgcn_s_barrier();
    asm volatile("" ::: "memory");
}

__device__ __forceinline__ void pf(WB& b, const float4* __restrict__ packW, int i, int w, int l) {
    const float4* p = packW + ((size_t)(i * 8 + w) * 18) * 64 + l;
#pragma unroll
    for (int j = 0; j < 18; ++j) b.v[j] = p[j * 64];
}

// ---------------- repack: swizzle weights into lane-major coalesced layout ----------------
__global__ void repack(const float* __restrict__ conv_k, const float* __restrict__ res_w,
                       const float* __restrict__ skip_w, const float* __restrict__ out0_w,
                       const float* __restrict__ out1_w, float* __restrict__ ws) {
    const int l = threadIdx.x;
    const int bb = blockIdx.x;
    float4* packW = (float4*)(ws + QFLOATS);
    float4* packH = packW + PACKW_F4;
    if (bb < NL * 8) {
        const int i = bb >> 3, w = bb & 7;
        float4* dst = packW + (size_t)bb * 18 * 64 + l;
        const int c  = w * 8 + (l & 7);
        const int kb = (l >> 3) * 16;
#pragma unroll
        for (int j = 0; j < 4; ++j) {           // conv col c
            float4 v;
            int k0 = kb + j * 4;
            v.x = conv_k[(((size_t)i * 2 + ((k0+0) >> 6)) * 64 + ((k0+0) & 63)) * 128 + c];
            v.y = conv_k[(((size_t)i * 2 + ((k0+1) >> 6)) * 64 + ((k0+1) & 63)) * 128 + c];
            v.z = conv_k[(((size_t)i * 2 + ((k0+2) >> 6)) * 64 + ((k0+2) & 63)) * 128 + c];
            v.w = conv_k[(((size_t)i * 2 + ((k0+3) >> 6)) * 64 + ((k0+3) & 63)) * 128 + c];
            dst[j * 64] = v;
        }
#pragma unroll
        for (int j = 0; j < 4; ++j) {           // conv col c+64
            float4 v;
            int k0 = kb + j * 4; int c2 = c + 64;
            v.x = conv_k[(((size_t)i * 2 + ((k0+0) >> 6)) * 64 + ((k0+0) & 63)) * 128 + c2];
            v.y = conv_k[(((size_t)i * 2 + ((k0+1) >> 6)) * 64 + ((k0+1) & 63)) * 128 + c2];
            v.z = conv_k[(((size_t)i * 2 + ((k0+2) >> 6)) * 64 + ((k0+2) & 63)) * 128 + c2];
            v.w = conv_k[(((size_t)i * 2 + ((k0+3) >> 6)) * 64 + ((k0+3) & 63)) * 128 + c2];
            dst[(4 + j) * 64] = v;
        }
        const int kr = (l >> 3) * 8;
#pragma unroll
        for (int j = 0; j < 2; ++j) {           // res col c
            float4 v; int k0 = kr + j * 4;
            v.x = res_w[((size_t)i * 64 + k0 + 0) * 64 + c];
            v.y = res_w[((size_t)i * 64 + k0 + 1) * 64 + c];
            v.z = res_w[((size_t)i * 64 + k0 + 2) * 64 + c];
            v.w = res_w[((size_t)i * 64 + k0 + 3) * 64 + c];
            dst[(8 + j) * 64] = v;
        }
        const int s0 = w * 32 + (l & 15) * 2;
        const int ks = (l >> 4) * 16;
#pragma unroll
        for (int j = 0; j < 4; ++j) {           // skip col s0
            float4 v; int k0 = ks + j * 4;
            v.x = skip_w[((size_t)i * 64 + k0 + 0) * 256 + s0];
            v.y = skip_w[((size_t)i * 64 + k0 + 1) * 256 + s0];
            v.z = skip_w[((size_t)i * 64 + k0 + 2) * 256 + s0];
            v.w = skip_w[((size_t)i * 64 + k0 + 3) * 256 + s0];
            dst[(10 + j) * 64] = v;
        }
#pragma unroll
        for (int j = 0; j < 4; ++j) {           // skip col s0+1
            float4 v; int k0 = ks + j * 4; int s1 = s0 + 1;
            v.x = skip_w[((size_t)i * 64 + k0 + 0) * 256 + s1];
            v.y = skip_w[((size_t)i * 64 + k0 + 1) * 256 + s1];
            v.z = skip_w[((size_t)i * 64 + k0 + 2) * 256 + s1];
            v.w = skip_w[((size_t)i * 64 + k0 + 3) * 256 + s1];
            dst[(14 + j) * 64] = v;
        }
    } else {
        const int hb = bb - NL * 8;             // 0..15: [which 0/1][wave]
        const int which = hb >> 3, w = hb & 7;
        const float* W = which ? out1_w : out0_w;
        float4* dst = packH + (size_t)hb * 32 * 64 + l;
        const int c  = w * 32 + (l & 31);
        const int kb = (l >> 5) * 128;
        for (int j = 0; j < 32; ++j) {
            float4 v; int k0 = kb + j * 4;
            v.x = W[(size_t)(k0 + 0) * 256 + c];
            v.y = W[(size_t)(k0 + 1) * 256 + c];
            v.z = W[(size_t)(k0 + 2) * 256 + c];
            v.w = W[(size_t)(k0 + 3) * 256 + c];
            dst[j * 64] = v;
        }
    }
}

// ---------------- main generator: one block per batch, 8 waves, 1 block/CU ----------------
// ring / packW / packH are SEPARATE __restrict__ params (all carved from d_ws on host):
// this lets the compiler keep pack prefetch loads in flight across ring stores.
__global__ __launch_bounds__(TPB, 1)
void wavenet_gen(const int* __restrict__ seed,
                 const float* __restrict__ embed,
                 const float* __restrict__ conv_b,
                 const float* __restrict__ res_b,
                 const float* __restrict__ skip_b,
                 const float* __restrict__ out0_b,
                 const float* __restrict__ out1_b,
                 const int* __restrict__ Tptr,
                 float* __restrict__ out,
                 float* __restrict__ ring,
                 const float4* __restrict__ packW,
                 const float4* __restrict__ packH)
{
    const int b   = blockIdx.x;
    const int tid = threadIdx.x;
    const int w   = tid >> 6;
    const int l   = tid & 63;
    const int T   = *Tptr;

    __shared__ __align__(16) float x2[128];          // [0:64) x_last, [64:128) x_cur
    __shared__ __align__(16) float gg[64];
    __shared__ __align__(16) float sk_lds[256];
    __shared__ __align__(16) float h0_lds[256];
    __shared__ __align__(16) float ebt[256 * 64];    // embed table
    __shared__ __align__(16) float cb[NL * 128];
    __shared__ __align__(16) float rb[NL * 64];
    __shared__ __align__(16) float o0b[256], o1b[256];
    __shared__ __align__(16) float sbt[256];         // sum over layers of skip_b
    __shared__ float wmaxv[8];
    __shared__ int   wmaxi[8];

    float* q = ring + (size_t)b * (QROWS * 64);

    // ---- init: zero queue rings (NT); stage LDS ----
    {
        vf4* q4 = (vf4*)q;
        const vf4 z = (vf4){0.f, 0.f, 0.f, 0.f};
        for (int idx = tid; idx < QROWS * 64 / 4; idx += TPB)
            __builtin_nontemporal_store(z, &q4[idx]);
        const float4* s4; float4* d4;
        s4 = (const float4*)embed;  d4 = (float4*)ebt;
        for (int idx = tid; idx < 256 * 64 / 4; idx += TPB) d4[idx] = s4[idx];
        s4 = (const float4*)conv_b; d4 = (float4*)cb;
        for (int idx = tid; idx < NL * 128 / 4; idx += TPB) d4[idx] = s4[idx];
        s4 = (const float4*)res_b;  d4 = (float4*)rb;
        for (int idx = tid; idx < NL * 64 / 4; idx += TPB) d4[idx] = s4[idx];
        s4 = (const float4*)out0_b; d4 = (float4*)o0b;
        for (int idx = tid; idx < 64; idx += TPB) d4[idx] = s4[idx];
        s4 = (const float4*)out1_b; d4 = (float4*)o1b;
        for (int idx = tid; idx < 64; idx += TPB) d4[idx] = s4[idx];
        if (tid < 256) {                               // sbt = sum_i skip_b[i]
            float acc = 0.f;
            for (int i = 0; i < NL; ++i) acc += skip_b[i * 256 + tid];
            sbt[tid] = acc;
        }
    }
    __syncthreads();
    if (tid < 64) {
        x2[tid] = 0.f;                                   // x_last(layer0, t=0) = 0
        const int smp = seed[b];
        x2[64 + tid] = ebt[smp * 64 + tid];              // x_cur = embed[seed]
    }
    __syncthreads();

    // double-buffered weight fragments: prefetch layer i+1 at top of layer i
    WB A, B;
    pf(A, packW, 0, w, l);

    float* out_pred = out + (size_t)b * T;
    float* out_log  = out + (size_t)NB * T + (size_t)b * T * 256;

    const int c   = w * 8 + (l & 7);       // conv/res column
    const int kb  = (l >> 3) * 16;         // conv K-chunk
    const int kr  = (l >> 3) * 8;          // res K-chunk
    const int ks  = (l >> 4) * 16;         // skip K-chunk
    const int s0  = w * 32 + (l & 15) * 2; // skip cols s0, s0+1
    const int c2  = w * 32 + (l & 31);     // head column
    const int kb2 = (l >> 5) * 128;        // head K-half

    for (int t = 0; t < T; ++t) {
        float skv0 = 0.f, skv1 = 0.f;

        auto layer = [&](WB& cur, WB& nxt, const int i) {
            const int inx = (i + 1 < NL) ? (i + 1) : 0;    // next layer (prefetch + ring read)
            // ---------------- phase alpha ----------------
            pf(nxt, packW, inx, w, l);                     // issue prefetch FIRST
            float xlnext = 0.f;
            if (w == 7) {                                  // early ring read: next layer's x_last
                const int d2 = 1 << (inx & 7);
                const int row2 = 255 * (inx >> 3) + (d2 - 1) + (t & (d2 - 1));
                xlnext = q[(size_t)row2 * 64 + l];
            }
            if (w == 6) {                                  // queue push of this layer's input
                const int d = 1 << (i & 7);
                const int row = 255 * (i >> 3) + (d - 1) + (t & (d - 1));
                q[(size_t)row * 64 + l] = x2[64 + l];
            }
            // conv partials (own 16-K chunk, cols c and c+64)
            float4 xk0 = *(const float4*)&x2[kb];
            float4 xk1 = *(const float4*)&x2[kb + 4];
            float4 xk2 = *(const float4*)&x2[kb + 8];
            float4 xk3 = *(const float4*)&x2[kb + 12];
            float4 aA = make_float4(0.f, 0.f, 0.f, 0.f);
            float4 aB = make_float4(0.f, 0.f, 0.f, 0.f);
            fma4(aA, xk0, cur.v[0]); fma4(aA, xk1, cur.v[1]);
            fma4(aA, xk2, cur.v[2]); fma4(aA, xk3, cur.v[3]);
            fma4(aB, xk0, cur.v[4]); fma4(aB, xk1, cur.v[5]);
            fma4(aB, xk2, cur.v[6]); fma4(aB, xk3, cur.v[7]);
            float hA = hadd4(aA), hB = hadd4(aB);
            hA += __shfl_xor(hA, 8);  hB += __shfl_xor(hB, 8);
            hA += __shfl_xor(hA, 16); hB += __shfl_xor(hB, 16);
            hA += __shfl_xor(hA, 32); hB += __shfl_xor(hB, 32);
            hA += cb[i * 128 + c];
            hB += cb[i * 128 + 64 + c];
            const float g = tanhf(hA) * (1.f / (1.f + expf(-hB)));
            if (l < 8) gg[w * 8 + l] = g;
            bar();
            // ---------------- phase beta ----------------
            // res partial
            float4 gr0 = *(const float4*)&gg[kr];
            float4 gr1 = *(const float4*)&gg[kr + 4];
            float4 ra = make_float4(0.f, 0.f, 0.f, 0.f);
            fma4(ra, gr0, cur.v[8]); fma4(ra, gr1, cur.v[9]);
            float racc = hadd4(ra);
            racc += __shfl_xor(racc, 8);
            racc += __shfl_xor(racc, 16);
            racc += __shfl_xor(racc, 32);
            const float xnew = x2[64 + c] + racc + rb[i * 64 + c];
            // skip partial
            float4 gs0 = *(const float4*)&gg[ks];
            float4 gs1 = *(const float4*)&gg[ks + 4];
            float4 gs2 = *(const float4*)&gg[ks + 8];
            float4 gs3 = *(const float4*)&gg[ks + 12];
            float4 sa0 = make_float4(0.f, 0.f, 0.f, 0.f);
            float4 sa1 = make_float4(0.f, 0.f, 0.f, 0.f);
            fma4(sa0, gs0, cur.v[10]); fma4(sa0, gs1, cur.v[11]);
            fma4(sa0, gs2, cur.v[12]); fma4(sa0, gs3, cur.v[13]);
            fma4(sa1, gs0, cur.v[14]); fma4(sa1, gs1, cur.v[15]);
            fma4(sa1, gs2, cur.v[16]); fma4(sa1, gs3, cur.v[17]);
            float ss0 = hadd4(sa0), ss1 = hadd4(sa1);
            ss0 += __shfl_xor(ss0, 16); ss1 += __shfl_xor(ss1, 16);
            ss0 += __shfl_xor(ss0, 32); ss1 += __shfl_xor(ss1, 32);
            skv0 += ss0;
            skv1 += ss1;
            if (l < 8) x2[64 + w * 8 + l] = xnew;   // residual out -> x_cur
            if (w == 7) x2[l] = xlnext;             // next layer's x_last
            bar();
        };

#pragma unroll 1
        for (int ii = 0; ii < NL; ii += 2) {
            layer(A, B, ii);
            layer(B, A, ii + 1);
        }

        // ---------------- head ----------------
        if (l < 16) { sk_lds[s0] = skv0 + sbt[s0]; sk_lds[s0 + 1] = skv1 + sbt[s0 + 1]; }
        bar();
        // GEMV1: h0 = relu(skip @ out0_w + b0)
        {
            const float4* hp = packH + ((size_t)w * 32) * 64 + l;
            float4 ha = make_float4(0.f, 0.f, 0.f, 0.f);
#pragma unroll 8
            for (int cc = 0; cc < 32; ++cc) {
                float4 wv = hp[cc * 64];
                float4 sv = *(const float4*)&sk_lds[kb2 + cc * 4];
                fma4(ha, sv, wv);
            }
            float hs = hadd4(ha);
            hs += __shfl_xor(hs, 32);
            const float h0 = fmaxf(hs + o0b[c2], 0.f);
            if (l < 32) h0_lds[c2] = h0;
        }
        bar();
        // GEMV2: logits = h0 @ out1_w + b1
        float logit;
        {
            const float4* hp = packH + ((size_t)(8 + w) * 32) * 64 + l;
            float4 la = make_float4(0.f, 0.f, 0.f, 0.f);
#pragma unroll 8
            for (int cc = 0; cc < 32; ++cc) {
                float4 wv = hp[cc * 64];
                float4 hv = *(const float4*)&h0_lds[kb2 + cc * 4];
                fma4(la, hv, wv);
            }
            float ls = hadd4(la);
            ls += __shfl_xor(ls, 32);
            logit = ls + o1b[c2];
            if (l < 32)
                __builtin_nontemporal_store(logit, &out_log[(size_t)t * 256 + c2]);
        }
        // wave-local argmax over its 32 columns (first-index tie-break)
        {
            float bv = logit; int bi = c2;
#pragma unroll
            for (int off = 1; off <= 16; off <<= 1) {
                const float ov = __shfl_xor(bv, off);
                const int   oi = __shfl_xor(bi, off);
                if (ov > bv || (ov == bv && oi < bi)) { bv = ov; bi = oi; }
            }
            if (l == 0) { wmaxv[w] = bv; wmaxi[w] = bi; }
        }
        bar();
        // final: cross-wave argmax, next-step state, mu-law output
        {
            float fv = wmaxv[0]; int fi = wmaxi[0];
#pragma unroll
            for (int ww = 1; ww < 8; ++ww) {
                const float vv = wmaxv[ww]; const int vi = wmaxi[ww];
                if (vv > fv || (vv == fv && vi < fi)) { fv = vv; fi = vi; }
            }
            if (tid < 64) x2[64 + tid] = ebt[fi * 64 + tid];
            if (tid == 0) {
                const float mw = (float)fi * (2.0f / 255.0f) - 1.0f;
                const float a  = fabsf(mw);
                const float p  = (exp2f(8.0f * a) - 1.0f) * (1.0f / 255.0f);
                __builtin_nontemporal_store((mw < 0.f) ? -p : p, &out_pred[t]);
            }
        }
        bar();
    }
}

extern "C" void kernel_launch(void* const* d_in, const int* in_sizes, int n_in,
                              void* d_out, int out_size, void* d_ws, size_t ws_size,
                              hipStream_t stream) {
    const int*   seed   = (const int*)  d_in[0];
    const float* embed  = (const float*)d_in[1];
    const float* conv_k = (const float*)d_in[2];
    const float* conv_b = (const float*)d_in[3];
    const float* res_w  = (const float*)d_in[4];
    const float* res_b  = (const float*)d_in[5];
    const float* skip_w = (const float*)d_in[6];
    const float* skip_b = (const float*)d_in[7];
    const float* out0_w = (const float*)d_in[8];
    const float* out0_b = (const float*)d_in[9];
    const float* out1_w = (const float*)d_in[10];
    const float* out1_b = (const float*)d_in[11];
    const int*   Tptr   = (const int*)  d_in[12];

    float* ws = (float*)d_ws;
    float* ring = ws;                                    // [64][765][64] fp32
    const float4* packW = (const float4*)(ws + QFLOATS); // layer weight pack
    const float4* packH = packW + PACKW_F4;              // head weight pack

    repack<<<dim3(NL * 8 + 16), dim3(64), 0, stream>>>(
        conv_k, res_w, skip_w, out0_w, out1_w, ws);

    wavenet_gen<<<dim3(NB), dim3(TPB), 0, stream>>>(
        seed, embed, conv_b, res_b, skip_b, out0_b, out1_b, Tptr,
        (float*)d_out, ring, packW, packH);
}

// Round 11
// 6563.417 us; speedup vs baseline: 1.9054x; 1.0058x over previous
//
#include <hip/hip_runtime.h>
#include <math.h>

#define NL 24
#define NB 64
#define TPB 512
#define QROWS 765
#define QFLOATS ((size_t)NB * QROWS * 64)         // ring: [64][765][64] fp32
#define PACKW_F4 ((size_t)NL * 8 * 18 * 64)       // per-lane packed layer weights (float4 units)

typedef float vf4 __attribute__((ext_vector_type(4)));

// Per-lane packed layer weights (18 float4 = 72 floats):
//  j=0..3   conv col c      = w*8+(l&7), k = (l>>3)*16 + ...   (k<64: tap0, k>=64: tap1)
//  j=4..7   conv col c+64
//  j=8..9   res  col c,      k = (l>>3)*8 + ...
//  j=10..13 skip col s0     = w*32+(l&15)*2
//  j=14..17 skip col s0+1
// Split into two register fragments to fit the ~128-VGPR scheduling budget:
struct WBc  { float4 v[8];  };   // conv  (32 VGPR) — double-buffered, 1 layer ahead
struct WBrs { float4 v[10]; };   // res+skip (40 VGPR) — single-buffered, issued mid-alpha

__device__ __forceinline__ float hadd4(float4 v) { return (v.x + v.y) + (v.z + v.w); }
__device__ __forceinline__ void fma4(float4& a, float4 x, float4 w) {
    a.x = fmaf(x.x, w.x, a.x); a.y = fmaf(x.y, w.y, a.y);
    a.z = fmaf(x.z, w.z, a.z); a.w = fmaf(x.w, w.w, a.w);
}

// Barrier that does NOT drain vmcnt (register weight prefetches stay in flight).
__device__ __forceinline__ void bar() {
    asm volatile("s_waitcnt lgkmcnt(0)" ::: "memory");
    __builtin_amdgcn_s_barrier();
    asm volatile("" ::: "memory");
}

__device__ __forceinline__ void pf_c(WBc& b, const float4* __restrict__ packW, int i, int w, int l) {
    const float4* p = packW + ((size_t)(i * 8 + w) * 18) * 64 + l;
#pragma unroll
    for (int j = 0; j < 8; ++j) b.v[j] = p[j * 64];
}
__device__ __forceinline__ void pf_rs(WBrs& b, const float4* __restrict__ packW, int i, int w, int l) {
    const float4* p = packW + ((size_t)(i * 8 + w) * 18) * 64 + l;
#pragma unroll
    for (int j = 0; j < 10; ++j) b.v[j] = p[(8 + j) * 64];
}

// ---------------- repack: swizzle weights into lane-major coalesced layout ----------------
__global__ void repack(const float* __restrict__ conv_k, const float* __restrict__ res_w,
                       const float* __restrict__ skip_w, const float* __restrict__ out0_w,
                       const float* __restrict__ out1_w, float* __restrict__ ws) {
    const int l = threadIdx.x;
    const int bb = blockIdx.x;
    float4* packW = (float4*)(ws + QFLOATS);
    float4* packH = packW + PACKW_F4;
    if (bb < NL * 8) {
        const int i = bb >> 3, w = bb & 7;
        float4* dst = packW + (size_t)bb * 18 * 64 + l;
        const int c  = w * 8 + (l & 7);
        const int kb = (l >> 3) * 16;
#pragma unroll
        for (int j = 0; j < 4; ++j) {           // conv col c
            float4 v;
            int k0 = kb + j * 4;
            v.x = conv_k[(((size_t)i * 2 + ((k0+0) >> 6)) * 64 + ((k0+0) & 63)) * 128 + c];
            v.y = conv_k[(((size_t)i * 2 + ((k0+1) >> 6)) * 64 + ((k0+1) & 63)) * 128 + c];
            v.z = conv_k[(((size_t)i * 2 + ((k0+2) >> 6)) * 64 + ((k0+2) & 63)) * 128 + c];
            v.w = conv_k[(((size_t)i * 2 + ((k0+3) >> 6)) * 64 + ((k0+3) & 63)) * 128 + c];
            dst[j * 64] = v;
        }
#pragma unroll
        for (int j = 0; j < 4; ++j) {           // conv col c+64
            float4 v;
            int k0 = kb + j * 4; int c2 = c + 64;
            v.x = conv_k[(((size_t)i * 2 + ((k0+0) >> 6)) * 64 + ((k0+0) & 63)) * 128 + c2];
            v.y = conv_k[(((size_t)i * 2 + ((k0+1) >> 6)) * 64 + ((k0+1) & 63)) * 128 + c2];
            v.z = conv_k[(((size_t)i * 2 + ((k0+2) >> 6)) * 64 + ((k0+2) & 63)) * 128 + c2];
            v.w = conv_k[(((size_t)i * 2 + ((k0+3) >> 6)) * 64 + ((k0+3) & 63)) * 128 + c2];
            dst[(4 + j) * 64] = v;
        }
        const int kr = (l >> 3) * 8;
#pragma unroll
        for (int j = 0; j < 2; ++j) {           // res col c
            float4 v; int k0 = kr + j * 4;
            v.x = res_w[((size_t)i * 64 + k0 + 0) * 64 + c];
            v.y = res_w[((size_t)i * 64 + k0 + 1) * 64 + c];
            v.z = res_w[((size_t)i * 64 + k0 + 2) * 64 + c];
            v.w = res_w[((size_t)i * 64 + k0 + 3) * 64 + c];
            dst[(8 + j) * 64] = v;
        }
        const int s0 = w * 32 + (l & 15) * 2;
        const int ks = (l >> 4) * 16;
#pragma unroll
        for (int j = 0; j < 4; ++j) {           // skip col s0
            float4 v; int k0 = ks + j * 4;
            v.x = skip_w[((size_t)i * 64 + k0 + 0) * 256 + s0];
            v.y = skip_w[((size_t)i * 64 + k0 + 1) * 256 + s0];
            v.z = skip_w[((size_t)i * 64 + k0 + 2) * 256 + s0];
            v.w = skip_w[((size_t)i * 64 + k0 + 3) * 256 + s0];
            dst[(10 + j) * 64] = v;
        }
#pragma unroll
        for (int j = 0; j < 4; ++j) {           // skip col s0+1
            float4 v; int k0 = ks + j * 4; int s1 = s0 + 1;
            v.x = skip_w[((size_t)i * 64 + k0 + 0) * 256 + s1];
            v.y = skip_w[((size_t)i * 64 + k0 + 1) * 256 + s1];
            v.z = skip_w[((size_t)i * 64 + k0 + 2) * 256 + s1];
            v.w = skip_w[((size_t)i * 64 + k0 + 3) * 256 + s1];
            dst[(14 + j) * 64] = v;
        }
    } else {
        const int hb = bb - NL * 8;             // 0..15: [which 0/1][wave]
        const int which = hb >> 3, w = hb & 7;
        const float* W = which ? out1_w : out0_w;
        float4* dst = packH + (size_t)hb * 32 * 64 + l;
        const int c  = w * 32 + (l & 31);
        const int kb = (l >> 5) * 128;
        for (int j = 0; j < 32; ++j) {
            float4 v; int k0 = kb + j * 4;
            v.x = W[(size_t)(k0 + 0) * 256 + c];
            v.y = W[(size_t)(k0 + 1) * 256 + c];
            v.z = W[(size_t)(k0 + 2) * 256 + c];
            v.w = W[(size_t)(k0 + 3) * 256 + c];
            dst[j * 64] = v;
        }
    }
}

// ---------------- main generator: one block per batch, 8 waves, 1 block/CU ----------------
__global__ __launch_bounds__(TPB, 1)
void wavenet_gen(const int* __restrict__ seed,
                 const float* __restrict__ embed,
                 const float* __restrict__ conv_b,
                 const float* __restrict__ res_b,
                 const float* __restrict__ skip_b,
                 const float* __restrict__ out0_b,
                 const float* __restrict__ out1_b,
                 const int* __restrict__ Tptr,
                 float* __restrict__ out,
                 float* __restrict__ ring,
                 const float4* __restrict__ packW,
                 const float4* __restrict__ packH)
{
    const int b   = blockIdx.x;
    const int tid = threadIdx.x;
    const int w   = tid >> 6;
    const int l   = tid & 63;
    const int T   = *Tptr;

    __shared__ __align__(16) float x2[128];          // [0:64) x_last, [64:128) x_cur
    __shared__ __align__(16) float gg[64];
    __shared__ __align__(16) float sk_lds[256];
    __shared__ __align__(16) float h0_lds[256];
    __shared__ __align__(16) float ebt[256 * 64];    // embed table
    __shared__ __align__(16) float cb[NL * 128];
    __shared__ __align__(16) float rb[NL * 64];
    __shared__ __align__(16) float o0b[256], o1b[256];
    __shared__ __align__(16) float sbt[256];         // sum over layers of skip_b
    __shared__ float wmaxv[8];
    __shared__ int   wmaxi[8];

    float* q = ring + (size_t)b * (QROWS * 64);

    // ---- init: zero queue rings (NT); stage LDS ----
    {
        vf4* q4 = (vf4*)q;
        const vf4 z = (vf4){0.f, 0.f, 0.f, 0.f};
        for (int idx = tid; idx < QROWS * 64 / 4; idx += TPB)
            __builtin_nontemporal_store(z, &q4[idx]);
        const float4* s4; float4* d4;
        s4 = (const float4*)embed;  d4 = (float4*)ebt;
        for (int idx = tid; idx < 256 * 64 / 4; idx += TPB) d4[idx] = s4[idx];
        s4 = (const float4*)conv_b; d4 = (float4*)cb;
        for (int idx = tid; idx < NL * 128 / 4; idx += TPB) d4[idx] = s4[idx];
        s4 = (const float4*)res_b;  d4 = (float4*)rb;
        for (int idx = tid; idx < NL * 64 / 4; idx += TPB) d4[idx] = s4[idx];
        s4 = (const float4*)out0_b; d4 = (float4*)o0b;
        for (int idx = tid; idx < 64; idx += TPB) d4[idx] = s4[idx];
        s4 = (const float4*)out1_b; d4 = (float4*)o1b;
        for (int idx = tid; idx < 64; idx += TPB) d4[idx] = s4[idx];
        if (tid < 256) {                               // sbt = sum_i skip_b[i]
            float acc = 0.f;
            for (int i = 0; i < NL; ++i) acc += skip_b[i * 256 + tid];
            sbt[tid] = acc;
        }
    }
    __syncthreads();
    if (tid < 64) {
        x2[tid] = 0.f;                                   // x_last(layer0, t=0) = 0
        const int smp = seed[b];
        x2[64 + tid] = ebt[smp * 64 + tid];              // x_cur = embed[seed]
    }
    __syncthreads();

    WBc  C0, C1;     // conv fragments, double-buffered (layer i from C[i&1])
    WBrs RS;         // res+skip fragment, single-buffered (loaded mid-alpha, used in beta)
    pf_c(C0, packW, 0, w, l);

    float* out_pred = out + (size_t)b * T;
    float* out_log  = out + (size_t)NB * T + (size_t)b * T * 256;

    const int c   = w * 8 + (l & 7);       // conv/res column
    const int kb  = (l >> 3) * 16;         // conv K-chunk
    const int kr  = (l >> 3) * 8;          // res K-chunk
    const int ks  = (l >> 4) * 16;         // skip K-chunk
    const int s0  = w * 32 + (l & 15) * 2; // skip cols s0, s0+1
    const int c2  = w * 32 + (l & 31);     // head column
    const int kb2 = (l >> 5) * 128;        // head K-half

    for (int t = 0; t < T; ++t) {
        float skv0 = 0.f, skv1 = 0.f;

        auto layer = [&](WBc& cur, WBc& nxt, const int i) {
            const int inx = (i + 1 < NL) ? (i + 1) : 0;
            // ---------------- phase alpha ----------------
            float xlnext = 0.f;
            if (w == 7) {                                  // early ring read: next layer's x_last
                const int d2 = 1 << (inx & 7);
                const int row2 = 255 * (inx >> 3) + (d2 - 1) + (t & (d2 - 1));
                xlnext = q[(size_t)row2 * 64 + l];
            }
            if (w == 6) {                                  // queue push of this layer's input
                const int d = 1 << (i & 7);
                const int row = 255 * (i >> 3) + (d - 1) + (t & (d - 1));
                q[(size_t)row * 64 + l] = x2[64 + l];
            }
            // conv partials (consumes cur; its loads were issued a full layer ago)
            float4 xk0 = *(const float4*)&x2[kb];
            float4 xk1 = *(const float4*)&x2[kb + 4];
            float4 xk2 = *(const float4*)&x2[kb + 8];
            float4 xk3 = *(const float4*)&x2[kb + 12];
            float4 aA = make_float4(0.f, 0.f, 0.f, 0.f);
            float4 aB = make_float4(0.f, 0.f, 0.f, 0.f);
            fma4(aA, xk0, cur.v[0]); fma4(aA, xk1, cur.v[1]);
            fma4(aA, xk2, cur.v[2]); fma4(aA, xk3, cur.v[3]);
            fma4(aB, xk0, cur.v[4]); fma4(aB, xk1, cur.v[5]);
            fma4(aB, xk2, cur.v[6]); fma4(aB, xk3, cur.v[7]);
            // cur is now dead: issue next conv (layer i+1) and this layer's res+skip
            pf_c(nxt, packW, inx, w, l);
            pf_rs(RS, packW, i, w, l);
            float hA = hadd4(aA), hB = hadd4(aB);
            hA += __shfl_xor(hA, 8);  hB += __shfl_xor(hB, 8);
            hA += __shfl_xor(hA, 16); hB += __shfl_xor(hB, 16);
            hA += __shfl_xor(hA, 32); hB += __shfl_xor(hB, 32);
            hA += cb[i * 128 + c];
            hB += cb[i * 128 + 64 + c];
            const float g = tanhf(hA) * (1.f / (1.f + expf(-hB)));
            if (l < 8) gg[w * 8 + l] = g;
            bar();
            // ---------------- phase beta ----------------
            // res partial (RS loads issued mid-alpha: ~1000+ cy of cover)
            float4 gr0 = *(const float4*)&gg[kr];
            float4 gr1 = *(const float4*)&gg[kr + 4];
            float4 ra = make_float4(0.f, 0.f, 0.f, 0.f);
            fma4(ra, gr0, RS.v[0]); fma4(ra, gr1, RS.v[1]);
            float racc = hadd4(ra);
            racc += __shfl_xor(racc, 8);
            racc += __shfl_xor(racc, 16);
            racc += __shfl_xor(racc, 32);
            const float xnew = x2[64 + c] + racc + rb[i * 64 + c];
            // skip partial
            float4 gs0 = *(const float4*)&gg[ks];
            float4 gs1 = *(const float4*)&gg[ks + 4];
            float4 gs2 = *(const float4*)&gg[ks + 8];
            float4 gs3 = *(const float4*)&gg[ks + 12];
            float4 sa0 = make_float4(0.f, 0.f, 0.f, 0.f);
            float4 sa1 = make_float4(0.f, 0.f, 0.f, 0.f);
            fma4(sa0, gs0, RS.v[2]); fma4(sa0, gs1, RS.v[3]);
            fma4(sa0, gs2, RS.v[4]); fma4(sa0, gs3, RS.v[5]);
            fma4(sa1, gs0, RS.v[6]); fma4(sa1, gs1, RS.v[7]);
            fma4(sa1, gs2, RS.v[8]); fma4(sa1, gs3, RS.v[9]);
            float ss0 = hadd4(sa0), ss1 = hadd4(sa1);
            ss0 += __shfl_xor(ss0, 16); ss1 += __shfl_xor(ss1, 16);
            ss0 += __shfl_xor(ss0, 32); ss1 += __shfl_xor(ss1, 32);
            skv0 += ss0;
            skv1 += ss1;
            if (l < 8) x2[64 + w * 8 + l] = xnew;   // residual out -> x_cur
            if (w == 7) x2[l] = xlnext;             // next layer's x_last
            bar();
        };

#pragma unroll 1
        for (int ii = 0; ii < NL; ii += 2) {
            layer(C0, C1, ii);
            layer(C1, C0, ii + 1);
        }

        // ---------------- head ----------------
        if (l < 16) { sk_lds[s0] = skv0 + sbt[s0]; sk_lds[s0 + 1] = skv1 + sbt[s0 + 1]; }
        bar();
        // GEMV1: h0 = relu(skip @ out0_w + b0)
        {
            const float4* hp = packH + ((size_t)w * 32) * 64 + l;
            float4 ha = make_float4(0.f, 0.f, 0.f, 0.f);
#pragma unroll 8
            for (int cc = 0; cc < 32; ++cc) {
                float4 wv = hp[cc * 64];
                float4 sv = *(const float4*)&sk_lds[kb2 + cc * 4];
                fma4(ha, sv, wv);
            }
            float hs = hadd4(ha);
            hs += __shfl_xor(hs, 32);
            const float h0 = fmaxf(hs + o0b[c2], 0.f);
            if (l < 32) h0_lds[c2] = h0;
        }
        bar();
        // GEMV2: logits = h0 @ out1_w + b1
        float logit;
        {
            const float4* hp = packH + ((size_t)(8 + w) * 32) * 64 + l;
            float4 la = make_float4(0.f, 0.f, 0.f, 0.f);
#pragma unroll 8
            for (int cc = 0; cc < 32; ++cc) {
                float4 wv = hp[cc * 64];
                float4 hv = *(const float4*)&h0_lds[kb2 + cc * 4];
                fma4(la, hv, wv);
            }
            float ls = hadd4(la);
            ls += __shfl_xor(ls, 32);
            logit = ls + o1b[c2];
            if (l < 32)
                __builtin_nontemporal_store(logit, &out_log[(size_t)t * 256 + c2]);
        }
        // wave-local argmax over its 32 columns (first-index tie-break)
        {
            float bv = logit; int bi = c2;
#pragma unroll
            for (int off = 1; off <= 16; off <<= 1) {
                const float ov = __shfl_xor(bv, off);
                const int   oi = __shfl_xor(bi, off);
                if (ov > bv || (ov == bv && oi < bi)) { bv = ov; bi = oi; }
            }
            if (l == 0) { wmaxv[w] = bv; wmaxi[w] = bi; }
        }
        bar();
        // final: cross-wave argmax, next-step state, mu-law output
        {
            float fv = wmaxv[0]; int fi = wmaxi[0];
#pragma unroll
            for (int ww = 1; ww < 8; ++ww) {
                const float vv = wmaxv[ww]; const int vi = wmaxi[ww];
                if (vv > fv || (vv == fv && vi < fi)) { fv = vv; fi = vi; }
            }
            if (tid < 64) x2[64 + tid] = ebt[fi * 64 + tid];
            if (tid == 0) {
                const float mw = (float)fi * (2.0f / 255.0f) - 1.0f;
                const float a  = fabsf(mw);
                const float p  = (exp2f(8.0f * a) - 1.0f) * (1.0f / 255.0f);
                __builtin_nontemporal_store((mw < 0.f) ? -p : p, &out_pred[t]);
            }
        }
        bar();
    }
}

extern "C" void kernel_launch(void* const* d_in, const int* in_sizes, int n_in,
                              void* d_out, int out_size, void* d_ws, size_t ws_size,
                              hipStream_t stream) {
    const int*   seed   = (const int*)  d_in[0];
    const float* embed  = (const float*)d_in[1];
    const float* conv_k = (const float*)d_in[2];
    const float* conv_b = (const float*)d_in[3];
    const float* res_w  = (const float*)d_in[4];
    const float* res_b  = (const float*)d_in[5];
    const float* skip_w = (const float*)d_in[6];
    const float* skip_b = (const float*)d_in[7];
    const float* out0_w = (const float*)d_in[8];
    const float* out0_b = (const float*)d_in[9];
    const float* out1_w = (const float*)d_in[10];
    const float* out1_b = (const float*)d_in[11];
    const int*   Tptr   = (const int*)  d_in[12];

    float* ws = (float*)d_ws;
    float* ring = ws;                                    // [64][765][64] fp32
    const float4* packW = (const float4*)(ws + QFLOATS); // layer weight pack
    const float4* packH = packW + PACKW_F4;              // head weight pack

    repack<<<dim3(NL * 8 + 16), dim3(64), 0, stream>>>(
        conv_k, res_w, skip_w, out0_w, out1_w, ws);

    wavenet_gen<<<dim3(NB), dim3(TPB), 0, stream>>>(
        seed, embed, conv_b, res_b, skip_b, out0_b, out1_b, Tptr,
        (float*)d_out, ring, packW, packH);
}

// Round 12
// 6379.395 us; speedup vs baseline: 1.9604x; 1.0288x over previous
//
#include <hip/hip_runtime.h>
#include <math.h>

#define NL 24
#define NB 64
#define TPB 512
#define QROWS 765
#define QFLOATS ((size_t)NB * QROWS * 64)         // ring: [64][765][64] fp32
#define PACKW_F4 ((size_t)NL * 8 * 18 * 64)       // per-lane packed layer weights (float4 units)

typedef float vf4 __attribute__((ext_vector_type(4)));

// Per-lane packed layer weights (18 float4 = 72 floats):
//  j=0..3   conv col c      = w*8+(l&7), k = (l>>3)*16 + ...   (k<64: tap0, k>=64: tap1)
//  j=4..7   conv col c+64
//  j=8..9   res  col c,      k = (l>>3)*8 + ...
//  j=10..13 skip col s0     = w*32+(l&15)*2
//  j=14..17 skip col s0+1
struct WBc  { float4 v[8];  };   // conv  (32 VGPR) — double-buffered, 1 layer ahead
struct WBrs { float4 v[10]; };   // res+skip (40 VGPR) — single-buffered, issued top-of-alpha

__device__ __forceinline__ float hadd4(float4 v) { return (v.x + v.y) + (v.z + v.w); }
__device__ __forceinline__ void fma4(float4& a, float4 x, float4 w) {
    a.x = fmaf(x.x, w.x, a.x); a.y = fmaf(x.y, w.y, a.y);
    a.z = fmaf(x.z, w.z, a.z); a.w = fmaf(x.w, w.w, a.w);
}

// Barrier that does NOT drain vmcnt (register weight prefetches stay in flight).
__device__ __forceinline__ void bar() {
    asm volatile("s_waitcnt lgkmcnt(0)" ::: "memory");
    __builtin_amdgcn_s_barrier();
    asm volatile("" ::: "memory");
}

__device__ __forceinline__ void pf_c(WBc& b, const float4* __restrict__ packW, int i, int w, int l) {
    const float4* p = packW + ((size_t)(i * 8 + w) * 18) * 64 + l;
#pragma unroll
    for (int j = 0; j < 8; ++j) b.v[j] = p[j * 64];
}
__device__ __forceinline__ void pf_rs(WBrs& b, const float4* __restrict__ packW, int i, int w, int l) {
    const float4* p = packW + ((size_t)(i * 8 + w) * 18) * 64 + l;
#pragma unroll
    for (int j = 0; j < 10; ++j) b.v[j] = p[(8 + j) * 64];
}

// ---------------- repack: swizzle weights into lane-major coalesced layout ----------------
__global__ void repack(const float* __restrict__ conv_k, const float* __restrict__ res_w,
                       const float* __restrict__ skip_w, const float* __restrict__ out0_w,
                       const float* __restrict__ out1_w, float* __restrict__ ws) {
    const int l = threadIdx.x;
    const int bb = blockIdx.x;
    float4* packW = (float4*)(ws + QFLOATS);
    float4* packH = packW + PACKW_F4;
    if (bb < NL * 8) {
        const int i = bb >> 3, w = bb & 7;
        float4* dst = packW + (size_t)bb * 18 * 64 + l;
        const int c  = w * 8 + (l & 7);
        const int kb = (l >> 3) * 16;
#pragma unroll
        for (int j = 0; j < 4; ++j) {           // conv col c
            float4 v;
            int k0 = kb + j * 4;
            v.x = conv_k[(((size_t)i * 2 + ((k0+0) >> 6)) * 64 + ((k0+0) & 63)) * 128 + c];
            v.y = conv_k[(((size_t)i * 2 + ((k0+1) >> 6)) * 64 + ((k0+1) & 63)) * 128 + c];
            v.z = conv_k[(((size_t)i * 2 + ((k0+2) >> 6)) * 64 + ((k0+2) & 63)) * 128 + c];
            v.w = conv_k[(((size_t)i * 2 + ((k0+3) >> 6)) * 64 + ((k0+3) & 63)) * 128 + c];
            dst[j * 64] = v;
        }
#pragma unroll
        for (int j = 0; j < 4; ++j) {           // conv col c+64
            float4 v;
            int k0 = kb + j * 4; int c2 = c + 64;
            v.x = conv_k[(((size_t)i * 2 + ((k0+0) >> 6)) * 64 + ((k0+0) & 63)) * 128 + c2];
            v.y = conv_k[(((size_t)i * 2 + ((k0+1) >> 6)) * 64 + ((k0+1) & 63)) * 128 + c2];
            v.z = conv_k[(((size_t)i * 2 + ((k0+2) >> 6)) * 64 + ((k0+2) & 63)) * 128 + c2];
            v.w = conv_k[(((size_t)i * 2 + ((k0+3) >> 6)) * 64 + ((k0+3) & 63)) * 128 + c2];
            dst[(4 + j) * 64] = v;
        }
        const int kr = (l >> 3) * 8;
#pragma unroll
        for (int j = 0; j < 2; ++j) {           // res col c
            float4 v; int k0 = kr + j * 4;
            v.x = res_w[((size_t)i * 64 + k0 + 0) * 64 + c];
            v.y = res_w[((size_t)i * 64 + k0 + 1) * 64 + c];
            v.z = res_w[((size_t)i * 64 + k0 + 2) * 64 + c];
            v.w = res_w[((size_t)i * 64 + k0 + 3) * 64 + c];
            dst[(8 + j) * 64] = v;
        }
        const int s0 = w * 32 + (l & 15) * 2;
        const int ks = (l >> 4) * 16;
#pragma unroll
        for (int j = 0; j < 4; ++j) {           // skip col s0
            float4 v; int k0 = ks + j * 4;
            v.x = skip_w[((size_t)i * 64 + k0 + 0) * 256 + s0];
            v.y = skip_w[((size_t)i * 64 + k0 + 1) * 256 + s0];
            v.z = skip_w[((size_t)i * 64 + k0 + 2) * 256 + s0];
            v.w = skip_w[((size_t)i * 64 + k0 + 3) * 256 + s0];
            dst[(10 + j) * 64] = v;
        }
#pragma unroll
        for (int j = 0; j < 4; ++j) {           // skip col s0+1
            float4 v; int k0 = ks + j * 4; int s1 = s0 + 1;
            v.x = skip_w[((size_t)i * 64 + k0 + 0) * 256 + s1];
            v.y = skip_w[((size_t)i * 64 + k0 + 1) * 256 + s1];
            v.z = skip_w[((size_t)i * 64 + k0 + 2) * 256 + s1];
            v.w = skip_w[((size_t)i * 64 + k0 + 3) * 256 + s1];
            dst[(14 + j) * 64] = v;
        }
    } else {
        const int hb = bb - NL * 8;             // 0..15: [which 0/1][wave]
        const int which = hb >> 3, w = hb & 7;
        const float* W = which ? out1_w : out0_w;
        float4* dst = packH + (size_t)hb * 32 * 64 + l;
        const int c  = w * 32 + (l & 31);
        const int kb = (l >> 5) * 128;
        for (int j = 0; j < 32; ++j) {
            float4 v; int k0 = kb + j * 4;
            v.x = W[(size_t)(k0 + 0) * 256 + c];
            v.y = W[(size_t)(k0 + 1) * 256 + c];
            v.z = W[(size_t)(k0 + 2) * 256 + c];
            v.w = W[(size_t)(k0 + 3) * 256 + c];
            dst[j * 64] = v;
        }
    }
}

// ---------------- main generator: one block per batch, 8 waves, 1 block/CU ----------------
__global__ __launch_bounds__(TPB, 1)
void wavenet_gen(const int* __restrict__ seed,
                 const float* __restrict__ embed,
                 const float* __restrict__ conv_b,
                 const float* __restrict__ res_b,
                 const float* __restrict__ skip_b,
                 const float* __restrict__ out0_b,
                 const float* __restrict__ out1_b,
                 const int* __restrict__ Tptr,
                 float* __restrict__ out,
                 float* __restrict__ ring,
                 const float4* __restrict__ packW,
                 const float4* __restrict__ packH)
{
    const int b   = blockIdx.x;
    const int tid = threadIdx.x;
    const int w   = tid >> 6;
    const int l   = tid & 63;
    const int T   = *Tptr;

    __shared__ __align__(16) float x2[128];          // [0:64) x_last, [64:128) x_cur
    __shared__ __align__(16) float gg[64];
    __shared__ __align__(16) float sk_lds[256];
    __shared__ __align__(16) float h0_lds[256];
    __shared__ __align__(16) float ebt[256 * 64];    // embed table
    __shared__ __align__(16) float cb[NL * 128];
    __shared__ __align__(16) float rb[NL * 64];
    __shared__ __align__(16) float o0b[256], o1b[256];
    __shared__ __align__(16) float sbt[256];         // sum over layers of skip_b
    __shared__ float wmaxv[8];
    __shared__ int   wmaxi[8];

    float* q = ring + (size_t)b * (QROWS * 64);

    // ---- init: zero queue rings (NT); stage LDS ----
    {
        vf4* q4 = (vf4*)q;
        const vf4 z = (vf4){0.f, 0.f, 0.f, 0.f};
        for (int idx = tid; idx < QROWS * 64 / 4; idx += TPB)
            __builtin_nontemporal_store(z, &q4[idx]);
        const float4* s4; float4* d4;
        s4 = (const float4*)embed;  d4 = (float4*)ebt;
        for (int idx = tid; idx < 256 * 64 / 4; idx += TPB) d4[idx] = s4[idx];
        s4 = (const float4*)conv_b; d4 = (float4*)cb;
        for (int idx = tid; idx < NL * 128 / 4; idx += TPB) d4[idx] = s4[idx];
        s4 = (const float4*)res_b;  d4 = (float4*)rb;
        for (int idx = tid; idx < NL * 64 / 4; idx += TPB) d4[idx] = s4[idx];
        s4 = (const float4*)out0_b; d4 = (float4*)o0b;
        for (int idx = tid; idx < 64; idx += TPB) d4[idx] = s4[idx];
        s4 = (const float4*)out1_b; d4 = (float4*)o1b;
        for (int idx = tid; idx < 64; idx += TPB) d4[idx] = s4[idx];
        if (tid < 256) {                               // sbt = sum_i skip_b[i]
            float acc = 0.f;
            for (int i = 0; i < NL; ++i) acc += skip_b[i * 256 + tid];
            sbt[tid] = acc;
        }
    }
    __syncthreads();
    if (tid < 64) {
        x2[tid] = 0.f;                                   // x_last(layer0, t=0) = 0
        const int smp = seed[b];
        x2[64 + tid] = ebt[smp * 64 + tid];              // x_cur = embed[seed]
    }
    __syncthreads();

    WBc  C0, C1;     // conv fragments, double-buffered (layer i from C[i&1])
    WBrs RS;         // res+skip fragment, single-buffered (issued top-of-alpha, used in beta)
    pf_c(C0, packW, 0, w, l);

    float* out_pred = out + (size_t)b * T;
    float* out_log  = out + (size_t)NB * T + (size_t)b * T * 256;

    const int c   = w * 8 + (l & 7);       // conv/res column
    const int kb  = (l >> 3) * 16;         // conv K-chunk
    const int kr  = (l >> 3) * 8;          // res K-chunk
    const int ks  = (l >> 4) * 16;         // skip K-chunk
    const int s0  = w * 32 + (l & 15) * 2; // skip cols s0, s0+1
    const int c2  = w * 32 + (l & 31);     // head column
    const int kb2 = (l >> 5) * 128;        // head K-half

    for (int t = 0; t < T; ++t) {
        float skv0 = 0.f, skv1 = 0.f;

        auto layer = [&](WBc& cur, WBc& nxt, const int i) {
            const int inx = (i + 1 < NL) ? (i + 1) : 0;
            // ---------------- phase alpha ----------------
            // Issue order matters for counted vmcnt waits:
            //   RS (used in beta) FIRST, conv-next (used next alpha) SECOND.
            // Beta's RS-wait then leaves the conv prefetch in flight.
            pf_rs(RS, packW, i, w, l);
            pf_c(nxt, packW, inx, w, l);
            float xlnext = 0.f;
            if (w == 7) {                                  // early ring read (NT: keep out of L2)
                const int d2 = 1 << (inx & 7);
                const int row2 = 255 * (inx >> 3) + (d2 - 1) + (t & (d2 - 1));
                xlnext = __builtin_nontemporal_load(&q[(size_t)row2 * 64 + l]);
            }
            if (w == 6) {                                  // queue push (NT: keep out of L2)
                const int d = 1 << (i & 7);
                const int row = 255 * (i >> 3) + (d - 1) + (t & (d - 1));
                __builtin_nontemporal_store(x2[64 + l], &q[(size_t)row * 64 + l]);
            }
            // conv partials (consumes cur; its loads were issued a full layer ago)
            float4 xk0 = *(const float4*)&x2[kb];
            float4 xk1 = *(const float4*)&x2[kb + 4];
            float4 xk2 = *(const float4*)&x2[kb + 8];
            float4 xk3 = *(const float4*)&x2[kb + 12];
            float4 aA = make_float4(0.f, 0.f, 0.f, 0.f);
            float4 aB = make_float4(0.f, 0.f, 0.f, 0.f);
            fma4(aA, xk0, cur.v[0]); fma4(aA, xk1, cur.v[1]);
            fma4(aA, xk2, cur.v[2]); fma4(aA, xk3, cur.v[3]);
            fma4(aB, xk0, cur.v[4]); fma4(aB, xk1, cur.v[5]);
            fma4(aB, xk2, cur.v[6]); fma4(aB, xk3, cur.v[7]);
            float hA = hadd4(aA), hB = hadd4(aB);
            hA += __shfl_xor(hA, 8);  hB += __shfl_xor(hB, 8);
            hA += __shfl_xor(hA, 16); hB += __shfl_xor(hB, 16);
            hA += __shfl_xor(hA, 32); hB += __shfl_xor(hB, 32);
            hA += cb[i * 128 + c];
            hB += cb[i * 128 + 64 + c];
            const float g = tanhf(hA) * (1.f / (1.f + expf(-hB)));
            if (l < 8) gg[w * 8 + l] = g;
            bar();
            // ---------------- phase beta ----------------
            // res partial (RS loads issued top-of-alpha: full phase of cover)
            float4 gr0 = *(const float4*)&gg[kr];
            float4 gr1 = *(const float4*)&gg[kr + 4];
            float4 ra = make_float4(0.f, 0.f, 0.f, 0.f);
            fma4(ra, gr0, RS.v[0]); fma4(ra, gr1, RS.v[1]);
            float racc = hadd4(ra);
            racc += __shfl_xor(racc, 8);
            racc += __shfl_xor(racc, 16);
            racc += __shfl_xor(racc, 32);
            const float xnew = x2[64 + c] + racc + rb[i * 64 + c];
            // skip partial
            float4 gs0 = *(const float4*)&gg[ks];
            float4 gs1 = *(const float4*)&gg[ks + 4];
            float4 gs2 = *(const float4*)&gg[ks + 8];
            float4 gs3 = *(const float4*)&gg[ks + 12];
            float4 sa0 = make_float4(0.f, 0.f, 0.f, 0.f);
            float4 sa1 = make_float4(0.f, 0.f, 0.f, 0.f);
            fma4(sa0, gs0, RS.v[2]); fma4(sa0, gs1, RS.v[3]);
            fma4(sa0, gs2, RS.v[4]); fma4(sa0, gs3, RS.v[5]);
            fma4(sa1, gs0, RS.v[6]); fma4(sa1, gs1, RS.v[7]);
            fma4(sa1, gs2, RS.v[8]); fma4(sa1, gs3, RS.v[9]);
            float ss0 = hadd4(sa0), ss1 = hadd4(sa1);
            ss0 += __shfl_xor(ss0, 16); ss1 += __shfl_xor(ss1, 16);
            ss0 += __shfl_xor(ss0, 32); ss1 += __shfl_xor(ss1, 32);
            skv0 += ss0;
            skv1 += ss1;
            if (l < 8) x2[64 + w * 8 + l] = xnew;   // residual out -> x_cur
            if (w == 7) x2[l] = xlnext;             // next layer's x_last
            bar();
        };

#pragma unroll 1
        for (int ii = 0; ii < NL; ii += 2) {
            layer(C0, C1, ii);
            layer(C1, C0, ii + 1);
        }

        // ---------------- head ----------------
        if (l < 16) { sk_lds[s0] = skv0 + sbt[s0]; sk_lds[s0 + 1] = skv1 + sbt[s0 + 1]; }
        bar();
        // GEMV1: h0 = relu(skip @ out0_w + b0)
        {
            const float4* hp = packH + ((size_t)w * 32) * 64 + l;
            float4 ha = make_float4(0.f, 0.f, 0.f, 0.f);
#pragma unroll 8
            for (int cc = 0; cc < 32; ++cc) {
                float4 wv = hp[cc * 64];
                float4 sv = *(const float4*)&sk_lds[kb2 + cc * 4];
                fma4(ha, sv, wv);
            }
            float hs = hadd4(ha);
            hs += __shfl_xor(hs, 32);
            const float h0 = fmaxf(hs + o0b[c2], 0.f);
            if (l < 32) h0_lds[c2] = h0;
        }
        bar();
        // GEMV2: logits = h0 @ out1_w + b1
        float logit;
        {
            const float4* hp = packH + ((size_t)(8 + w) * 32) * 64 + l;
            float4 la = make_float4(0.f, 0.f, 0.f, 0.f);
#pragma unroll 8
            for (int cc = 0; cc < 32; ++cc) {
                float4 wv = hp[cc * 64];
                float4 hv = *(const float4*)&h0_lds[kb2 + cc * 4];
                fma4(la, hv, wv);
            }
            float ls = hadd4(la);
            ls += __shfl_xor(ls, 32);
            logit = ls + o1b[c2];
            if (l < 32)
                __builtin_nontemporal_store(logit, &out_log[(size_t)t * 256 + c2]);
        }
        // wave-local argmax over its 32 columns (first-index tie-break)
        {
            float bv = logit; int bi = c2;
#pragma unroll
            for (int off = 1; off <= 16; off <<= 1) {
                const float ov = __shfl_xor(bv, off);
                const int   oi = __shfl_xor(bi, off);
                if (ov > bv || (ov == bv && oi < bi)) { bv = ov; bi = oi; }
            }
            if (l == 0) { wmaxv[w] = bv; wmaxi[w] = bi; }
        }
        bar();
        // final: cross-wave argmax, next-step state, mu-law output
        {
            float fv = wmaxv[0]; int fi = wmaxi[0];
#pragma unroll
            for (int ww = 1; ww < 8; ++ww) {
                const float vv = wmaxv[ww]; const int vi = wmaxi[ww];
                if (vv > fv || (vv == fv && vi < fi)) { fv = vv; fi = vi; }
            }
            if (tid < 64) x2[64 + tid] = ebt[fi * 64 + tid];
            if (tid == 0) {
                const float mw = (float)fi * (2.0f / 255.0f) - 1.0f;
                const float a  = fabsf(mw);
                const float p  = (exp2f(8.0f * a) - 1.0f) * (1.0f / 255.0f);
                __builtin_nontemporal_store((mw < 0.f) ? -p : p, &out_pred[t]);
            }
        }
        bar();
    }
}

extern "C" void kernel_launch(void* const* d_in, const int* in_sizes, int n_in,
                              void* d_out, int out_size, void* d_ws, size_t ws_size,
                              hipStream_t stream) {
    const int*   seed   = (const int*)  d_in[0];
    const float* embed  = (const float*)d_in[1];
    const float* conv_k = (const float*)d_in[2];
    const float* conv_b = (const float*)d_in[3];
    const float* res_w  = (const float*)d_in[4];
    const float* res_b  = (const float*)d_in[5];
    const float* skip_w = (const float*)d_in[6];
    const float* skip_b = (const float*)d_in[7];
    const float* out0_w = (const float*)d_in[8];
    const float* out0_b = (const float*)d_in[9];
    const float* out1_w = (const float*)d_in[10];
    const float* out1_b = (const float*)d_in[11];
    const int*   Tptr   = (const int*)  d_in[12];

    float* ws = (float*)d_ws;
    float* ring = ws;                                    // [64][765][64] fp32
    const float4* packW = (const float4*)(ws + QFLOATS); // layer weight pack
    const float4* packH = packW + PACKW_F4;              // head weight pack

    repack<<<dim3(NL * 8 + 16), dim3(64), 0, stream>>>(
        conv_k, res_w, skip_w, out0_w, out1_w, ws);

    wavenet_gen<<<dim3(NB), dim3(TPB), 0, stream>>>(
        seed, embed, conv_b, res_b, skip_b, out0_b, out1_b, Tptr,
        (float*)d_out, ring, packW, packH);
}